// Round 1
// 598.572 us; speedup vs baseline: 1.1178x; 1.1178x over previous
//
#include <hip/hip_runtime.h>
#include <math.h>

// Problem constants
#define L4   4
#define CPL  1024
#define HID  1024
#define IND  512
#define MLPD 128
#define OUTD 512
#define G3   3072
#define ROWS 4096   // L4*CPL
#define KP   544    // padded gi K: 512 OUT + 1 tension + 31 zeros

typedef unsigned short u16;
typedef u16   u16x8  __attribute__((ext_vector_type(8)));
typedef short bf16x8 __attribute__((ext_vector_type(8)));
typedef float f32x4  __attribute__((ext_vector_type(4)));

__device__ __forceinline__ float b2f(u16 u) {
  return __uint_as_float(((unsigned int)u) << 16);
}
__device__ __forceinline__ u16 f2b(float f) {   // round-to-nearest-even
  unsigned int x = __float_as_uint(f);
  x += 0x7fffu + ((x >> 16) & 1u);
  return (u16)(x >> 16);
}
__device__ __forceinline__ float sigm(float v) { return 1.0f/(1.0f + expf(-v)); }

// ---- dual-dtype access helpers: f32 flag selects float32 vs bf16 layout ----
struct F4 { float x, y, z, w; };
__device__ __forceinline__ F4 ld4(const void* p, size_t i, bool f32) {
  F4 r;
  if (f32) {
    float4 v = *reinterpret_cast<const float4*>((const float*)p + i);
    r.x = v.x; r.y = v.y; r.z = v.z; r.w = v.w;
  } else {
    ushort4 v = *reinterpret_cast<const ushort4*>((const u16*)p + i);
    r.x = b2f(v.x); r.y = b2f(v.y); r.z = b2f(v.z); r.w = b2f(v.w);
  }
  return r;
}
__device__ __forceinline__ float ld1(const void* p, size_t i, bool f32) {
  return f32 ? ((const float*)p)[i] : b2f(((const u16*)p)[i]);
}
__device__ __forceinline__ void st1(void* p, size_t i, float v, bool f32) {
  if (f32) ((float*)p)[i] = v; else ((u16*)p)[i] = f2b(v);
}
// load 8 elems -> bf16 bits (converting if fp32). i must be multiple of 8.
__device__ __forceinline__ u16x8 ldc8(const void* p, size_t i, bool f32) {
  u16x8 r;
  if (f32) {
    const float* q = (const float*)p + i;
    float4 v0 = *reinterpret_cast<const float4*>(q);
    float4 v1 = *reinterpret_cast<const float4*>(q + 4);
    r[0]=f2b(v0.x); r[1]=f2b(v0.y); r[2]=f2b(v0.z); r[3]=f2b(v0.w);
    r[4]=f2b(v1.x); r[5]=f2b(v1.y); r[6]=f2b(v1.z); r[7]=f2b(v1.w);
  } else {
    r = *reinterpret_cast<const u16x8*>((const u16*)p + i);
  }
  return r;
}

// ---------------- dtype detector ----------------
__global__ void k_detect(const void* __restrict__ x, int* __restrict__ flag) {
  int t = threadIdx.x;   // 256
  const u16* xu = (const u16*)x;
  unsigned u = xu[2*t];
  int e = (u >> 7) & 0xFF;
  int good = (e >= 96 && e <= 134) ? 1 : 0;
  __shared__ int cnt[256];
  cnt[t] = good;
  __syncthreads();
  for (int s = 128; s > 0; s >>= 1) { if (t < s) cnt[t] += cnt[t+s]; __syncthreads(); }
  if (t == 0) flag[0] = (cnt[0] < 200) ? 1 : 0;   // 1 = float32, 0 = bf16
}

// ---------------- prep: zero accumulators + bias sums ----------------
__global__ void k_prep(float* __restrict__ zf, const void* __restrict__ bih,
                       const void* __restrict__ bhh, const int* __restrict__ dflag,
                       float* __restrict__ bs_r, float* __restrict__ bs_z,
                       float* __restrict__ bn_i, float* __restrict__ bn_h) {
  const bool f32 = dflag[0] != 0;
  int b = blockIdx.x, t = threadIdx.x;
  if (b < 16) {
    int idx = b*256 + t;          // [0,4096)
    int l = idx >> 10, j = idx & 1023;
    bs_r[idx] = ld1(bih, l*G3 + j, f32)        + ld1(bhh, l*G3 + j, f32);
    bs_z[idx] = ld1(bih, l*G3 + 1024 + j, f32) + ld1(bhh, l*G3 + 1024 + j, f32);
    bn_i[idx] = ld1(bih, l*G3 + 2048 + j, f32);
    bn_h[idx] = ld1(bhh, l*G3 + 2048 + j, f32);
  } else {
    int idx = (b-16)*256 + t;     // [0,12288)
    zf[idx] = 0.0f;
  }
}

// ---------------- repack Wih -> bf16 [4][3072][544] (col 512 = tension wt) ----
__global__ void k_prep_wih(const void* __restrict__ Wih, const int* __restrict__ dflag,
                           u16* __restrict__ WihP) {
  const bool f32 = dflag[0] != 0;
  int row = blockIdx.x;            // 0..12287 == l*3072+g
  int t = threadIdx.x;
  size_t src = (size_t)row * 513;
  size_t dst = (size_t)row * KP;
  WihP[dst + t]       = f2b(ld1(Wih, src + t, f32));
  WihP[dst + 256 + t] = f2b(ld1(Wih, src + 256 + t, f32));
  if (t < 32) {
    float v = (t == 0) ? ld1(Wih, src + 512, f32) : 0.0f;
    WihP[dst + 512 + t] = f2b(v);
  }
}

// ---------------- repack W1 hidden part -> bf16 transposed W1T[l][path*128+m][k] ----
// src: W1[l][512+k][m]  (k in [0,1024), m in [0,128))
__global__ void k_prep_w1t(const void* __restrict__ eaW1, const void* __restrict__ egW1,
                           const int* __restrict__ dflag, u16* __restrict__ W1T) {
  const bool f32 = dflag[0] != 0;
  __shared__ u16 sT[128*130];
  int l = blockIdx.x, path = blockIdx.y, kt = blockIdx.z;   // (4,2,8)
  int t = threadIdx.x;
  const void* W1 = path ? egW1 : eaW1;
  // read 128 k-rows x 128 m (coalesced over m), store transposed in LDS
  for (int rr = 0; rr < 128; rr += 2) {
    int r = rr + (t >> 7), m = t & 127;
    float v = ld1(W1, ((size_t)l*1536 + 512 + kt*128 + r)*MLPD + m, f32);
    sT[m*130 + r] = f2b(v);
  }
  __syncthreads();
  // write rows of W1T (coalesced over k)
  for (int mm = 0; mm < 128; mm += 2) {
    int m = mm + (t >> 7), kk = t & 127;
    W1T[((size_t)l*256 + path*128 + m)*1024 + kt*128 + kk] = sT[m*130 + kk];
  }
}

// ---------------- base accumulation (x part of encoder layer 1) ----------------
__global__ void k_base_acc(const void* __restrict__ x, const void* __restrict__ eaW1,
                           const void* __restrict__ egW1, const int* __restrict__ dflag,
                           float* __restrict__ baseacc) {
  const bool f32 = dflag[0] != 0;
  int l = blockIdx.x, path = blockIdx.y, kc = blockIdx.z, m = threadIdx.x; // 128 thr
  const void* W1 = path ? egW1 : eaW1;
  float acc = 0.0f;
  int i0 = kc*128;
  for (int i = i0; i < i0 + 128; ++i)
    acc += ld1(x, i, f32) * ld1(W1, ((size_t)l*1536 + i)*MLPD + m, f32);
  atomicAdd(&baseacc[path*512 + l*MLPD + m], acc);
}

// ---------------- MFMA k_z: Z = relu(base + b1 + H @ W1T^T) ----------------
// A = H [4096,1024] (dual), B = W1T [l][256][1024] bf16 (NT). Tile 64x64, 4 waves 2x2.
#define LPAD 40
__global__ __launch_bounds__(256) void k_z_mfma(
    const void* __restrict__ H, const u16* __restrict__ W1T,
    const void* __restrict__ eab1, const void* __restrict__ egb1,
    const float* __restrict__ baseacc, const int* __restrict__ dflag,
    u16* __restrict__ Z) {
  const bool f32 = dflag[0] != 0;
  __shared__ u16 sA[64*LPAD];
  __shared__ u16 sB[64*LPAD];
  int t = threadIdx.x;
  int row0 = blockIdx.x * 64;
  int n0   = blockIdx.y * 64;          // 0,64,128,192
  int l    = row0 >> 10;
  int wid = t >> 6, lane = t & 63;
  int waveM = wid >> 1, waveN = wid & 1;
  int quad = lane >> 4, lcol = lane & 15;
  int arow = t >> 2, kq = (t & 3) * 8;

  f32x4 acc[2][2];
  const f32x4 zz = {0.0f,0.0f,0.0f,0.0f};
#pragma unroll
  for (int i = 0; i < 2; ++i)
#pragma unroll
    for (int j = 0; j < 2; ++j) acc[i][j] = zz;

  size_t habase = (size_t)(row0 + arow)*HID;
  const u16* Bb = W1T + ((size_t)l*256 + n0 + arow)*1024;

  u16x8 av = ldc8(H, habase + kq, f32);
  u16x8 bv = *reinterpret_cast<const u16x8*>(Bb + kq);
  for (int k0 = 0; k0 < HID; k0 += 32) {
    __syncthreads();
    *reinterpret_cast<u16x8*>(&sA[arow*LPAD + kq]) = av;
    *reinterpret_cast<u16x8*>(&sB[arow*LPAD + kq]) = bv;
    __syncthreads();
    if (k0 + 32 < HID) {
      av = ldc8(H, habase + k0 + 32 + kq, f32);
      bv = *reinterpret_cast<const u16x8*>(Bb + k0 + 32 + kq);
    }
    bf16x8 af[2];
#pragma unroll
    for (int i = 0; i < 2; ++i)
      af[i] = *reinterpret_cast<const bf16x8*>(&sA[(waveM*32 + i*16 + lcol)*LPAD + quad*8]);
#pragma unroll
    for (int j = 0; j < 2; ++j) {
      bf16x8 bf = *reinterpret_cast<const bf16x8*>(&sB[(waveN*32 + j*16 + lcol)*LPAD + quad*8]);
#pragma unroll
      for (int i = 0; i < 2; ++i)
        acc[i][j] = __builtin_amdgcn_mfma_f32_16x16x32_bf16(af[i], bf, acc[i][j], 0, 0, 0);
    }
  }
  // epilogue: + base + b1, relu, store
#pragma unroll
  for (int j = 0; j < 2; ++j) {
    int nn = n0 + waveN*32 + j*16 + lcol;
    int path = nn >> 7, m = nn & 127;
    float bval = baseacc[path*512 + l*MLPD + m] +
                 ld1(path ? egb1 : eab1, l*MLPD + m, f32);
#pragma unroll
    for (int i = 0; i < 2; ++i)
#pragma unroll
      for (int g = 0; g < 4; ++g) {
        int r = row0 + waveM*32 + i*16 + quad*4 + g;
        float v = acc[i][j][g] + bval;
        Z[(size_t)r*256 + nn] = f2b(v > 0.0f ? v : 0.0f);
      }
  }
}

// ---------------- VALU k_out (small): OUT = Za@W2a - Zg@W2g + bias diff ----------------
#define BM 64
#define BN 64
#define BK 16
__global__ __launch_bounds__(256) void k_out(
    const u16* __restrict__ Zb, const void* __restrict__ eaW2, const void* __restrict__ egW2,
    const void* __restrict__ eab2, const void* __restrict__ egb2,
    const int* __restrict__ dflag, u16* __restrict__ OUTT) {
  const bool f32 = dflag[0] != 0;
  __shared__ float As[BK][BM];
  __shared__ float Bs[BK][BN];
  int t = threadIdx.x;
  int row0 = blockIdx.x * BM;
  int n0   = blockIdx.y * BN;          // 0..448
  int l    = row0 >> 10;
  const u16* Ab = Zb + (size_t)row0 * 256;
  int tx = t & 15, ty = t >> 4;
  int am = t >> 2, akq = (t & 3) * 4;
  int bk = t >> 4, bn = (t & 15) * 4;

  float acc[4][4];
#pragma unroll
  for (int j = 0; j < 4; ++j) {
    int o = n0 + tx*4 + j;
    float bd = ld1(eab2, l*OUTD + o, f32) - ld1(egb2, l*OUTD + o, f32);
#pragma unroll
    for (int i = 0; i < 4; ++i) acc[i][j] = bd;
  }
  for (int ph = 0; ph < 2; ++ph) {
    const void* B = ph ? egW2 : eaW2;
    size_t boff = (size_t)l*MLPD*OUTD + n0;
    float sgn = ph ? -1.0f : 1.0f;
    for (int k0 = 0; k0 < MLPD; k0 += BK) {
      ushort4 avu = *reinterpret_cast<const ushort4*>(Ab + (size_t)am*256 + ph*128 + k0 + akq);
      F4 bvf = ld4(B, boff + (size_t)(k0 + bk)*OUTD + bn, f32);
      __syncthreads();
      As[akq+0][am] = b2f(avu.x); As[akq+1][am] = b2f(avu.y);
      As[akq+2][am] = b2f(avu.z); As[akq+3][am] = b2f(avu.w);
      Bs[bk][bn+0] = sgn*bvf.x; Bs[bk][bn+1] = sgn*bvf.y;
      Bs[bk][bn+2] = sgn*bvf.z; Bs[bk][bn+3] = sgn*bvf.w;
      __syncthreads();
#pragma unroll
      for (int kk = 0; kk < BK; ++kk) {
        float4 a4 = *reinterpret_cast<const float4*>(&As[kk][ty*4]);
        float4 b4 = *reinterpret_cast<const float4*>(&Bs[kk][tx*4]);
        float a[4] = {a4.x,a4.y,a4.z,a4.w};
        float b[4] = {b4.x,b4.y,b4.z,b4.w};
#pragma unroll
        for (int i = 0; i < 4; ++i)
#pragma unroll
          for (int j = 0; j < 4; ++j) acc[i][j] += a[i]*b[j];
      }
    }
  }
#pragma unroll
  for (int i = 0; i < 4; ++i) {
    int r = row0 + ty*4 + i;
#pragma unroll
    for (int j = 0; j < 4; ++j)
      OUTT[(size_t)r*KP + n0 + tx*4 + j] = f2b(acc[i][j]);
  }
}

// tension -> OUTT col 512 (bf16); zero pad cols 513..543; tsum += sumsq(row)
__global__ void k_tension(u16* __restrict__ OUTT, float* __restrict__ tsum) {
  int row = blockIdx.x, t = threadIdx.x;
  u16* p = OUTT + (size_t)row*KP;
  float v0 = b2f(p[t]), v1 = b2f(p[t+256]);
  float s = v0*v0 + v1*v1;
#pragma unroll
  for (int off = 32; off > 0; off >>= 1) s += __shfl_down(s, off, 64);
  __shared__ float red[4];
  if ((t & 63) == 0) red[t >> 6] = s;
  __syncthreads();
  if (t == 0) {
    float tot = red[0] + red[1] + red[2] + red[3];
    p[512] = f2b(tot * (1.0f/512.0f));
    atomicAdd(tsum, tot);
  }
  if (t < 31) p[513 + t] = 0;
}

// ---------------- fused MFMA GRU v2: 128x64 tile, BK=64, XOR-swizzled LDS ----
// Per block: 128 rows x 64 j-cols x {r,z,n} bands. 4 waves, each 64x32.
// LDS rows are 128 B; swizzle byte^=((row&7)<<4) kills ds_read_b128 conflicts
// (guide G4 verified recipe for 128 B-stride rows). Register-staged (dual dtype),
// prefetch one K-step ahead, 2 barriers per BK=64 (was per BK=32).
#define SWZ(row, ku) ((row)*64 + ((ku) ^ (((row)&7)<<3)))
__global__ __launch_bounds__(256, 2) void k_gru_mfma(
    const u16* __restrict__ OUTT, const void* __restrict__ H,
    const u16* __restrict__ WihP, const void* __restrict__ Whh,
    const float* __restrict__ bs_r, const float* __restrict__ bs_z,
    const float* __restrict__ bn_i, const float* __restrict__ bn_h,
    const int* __restrict__ dflag, void* __restrict__ outv) {
  const bool f32 = dflag[0] != 0;
  __shared__ __align__(16) u16 sA[128*64];     // 16 KB
  __shared__ __align__(16) u16 sB[3*64*64];    // 24 KB
  int t = threadIdx.x;
  // XCD swizzle (512 blocks, 512%8==0 -> bijective): xg = XCD id.
  // Each XCD owns one (level, j-half): B panel stays L2-local.
  int bid = blockIdx.x;
  int xg = bid & 7, inner = bid >> 3;      // inner 0..63
  int l = xg & 3, jG = xg >> 2;
  int rbi = inner & 7, jbl = inner >> 3;   // 8 row-blocks, 8 j-blocks
  int row0 = (l*8 + rbi) * 128;
  int j0   = (jG*8 + jbl) * 64;
  int wid = t >> 6, lane = t & 63;
  int waveM = wid & 1, waveJ = wid >> 1;   // 2x2 waves over 128x64
  int quad = lane >> 4, lcol = lane & 15;

  f32x4 acc[4][4][2];   // band {r,z,i_n,h_n} x 4 m-frags x 2 j-frags
  const f32x4 zz = {0.0f,0.0f,0.0f,0.0f};
#pragma unroll
  for (int b = 0; b < 4; ++b)
#pragma unroll
    for (int i = 0; i < 4; ++i)
#pragma unroll
      for (int j = 0; j < 2; ++j) acc[b][i][j] = zz;

  // staging decomposition (per thread): A: 4 chunks, B: 6 chunks of u16x8.
  // idx = s*256+t;  A: row=idx>>3 (0..127), ch=idx&7;  B: band=idx>>9,
  // row=(idx&511)>>3 (0..63), ch=idx&7.  8 threads/row -> 128 B coalesced.

  // ---- GEMM1: gi over K=544 (pure bf16; last step kw=32, rest zero-padded) ----
  {
    u16x8 ra[4], rbr[6];
    auto load1 = [&](int k0, int kw) {
#pragma unroll
      for (int s = 0; s < 4; ++s) {
        int idx = s*256 + t, row = idx >> 3, ch = idx & 7;
        if (ch*8 < kw)
          ra[s] = *reinterpret_cast<const u16x8*>(
              OUTT + (size_t)(row0 + row)*KP + k0 + ch*8);
        else { u16x8 z = {0,0,0,0,0,0,0,0}; ra[s] = z; }
      }
#pragma unroll
      for (int s = 0; s < 6; ++s) {
        int idx = s*256 + t, band = idx >> 9, rem = idx & 511;
        int row = rem >> 3, ch = rem & 7;
        if (ch*8 < kw)
          rbr[s] = *reinterpret_cast<const u16x8*>(
              WihP + ((size_t)l*G3 + band*1024 + j0 + row)*KP + k0 + ch*8);
        else { u16x8 z = {0,0,0,0,0,0,0,0}; rbr[s] = z; }
      }
    };
    load1(0, 64);
    for (int k0 = 0; k0 < KP; k0 += 64) {
      int kw = (KP - k0 >= 64) ? 64 : (KP - k0);
      __syncthreads();
#pragma unroll
      for (int s = 0; s < 4; ++s) {
        int idx = s*256 + t, row = idx >> 3, ch = idx & 7;
        *reinterpret_cast<u16x8*>(&sA[SWZ(row, ch*8)]) = ra[s];
      }
#pragma unroll
      for (int s = 0; s < 6; ++s) {
        int idx = s*256 + t, band = idx >> 9, rem = idx & 511;
        int row = rem >> 3, ch = rem & 7;
        *reinterpret_cast<u16x8*>(&sB[band*4096 + SWZ(row, ch*8)]) = rbr[s];
      }
      __syncthreads();
      if (k0 + 64 < KP) {
        int kn = k0 + 64;
        load1(kn, (KP - kn >= 64) ? 64 : (KP - kn));
      }
#pragma unroll
      for (int kc = 0; kc < 2; ++kc) {
        if (kc*32 < kw) {
          bf16x8 af[4];
#pragma unroll
          for (int i = 0; i < 4; ++i) {
            int rl = waveM*64 + i*16 + lcol;
            af[i] = *reinterpret_cast<const bf16x8*>(&sA[SWZ(rl, kc*32 + quad*8)]);
          }
#pragma unroll
          for (int b = 0; b < 3; ++b)
#pragma unroll
            for (int jj = 0; jj < 2; ++jj) {
              int jl = waveJ*32 + jj*16 + lcol;
              bf16x8 bf = *reinterpret_cast<const bf16x8*>(
                  &sB[b*4096 + SWZ(jl, kc*32 + quad*8)]);
#pragma unroll
              for (int i = 0; i < 4; ++i)
                acc[b][i][jj] = __builtin_amdgcn_mfma_f32_16x16x32_bf16(
                    af[i], bf, acc[b][i][jj], 0, 0, 0);
            }
        }
      }
    }
  }
  // ---- GEMM2: gh over K=1024 (dual-dtype converted on stage) ----
  {
    u16x8 ra[4], rbr[6];
    auto load2 = [&](int k0) {
#pragma unroll
      for (int s = 0; s < 4; ++s) {
        int idx = s*256 + t, row = idx >> 3, ch = idx & 7;
        ra[s] = ldc8(H, (size_t)(row0 + row)*HID + k0 + ch*8, f32);
      }
#pragma unroll
      for (int s = 0; s < 6; ++s) {
        int idx = s*256 + t, band = idx >> 9, rem = idx & 511;
        int row = rem >> 3, ch = rem & 7;
        rbr[s] = ldc8(Whh, ((size_t)l*G3 + band*1024 + j0 + row)*HID + k0 + ch*8, f32);
      }
    };
    load2(0);
    for (int k0 = 0; k0 < HID; k0 += 64) {
      __syncthreads();
#pragma unroll
      for (int s = 0; s < 4; ++s) {
        int idx = s*256 + t, row = idx >> 3, ch = idx & 7;
        *reinterpret_cast<u16x8*>(&sA[SWZ(row, ch*8)]) = ra[s];
      }
#pragma unroll
      for (int s = 0; s < 6; ++s) {
        int idx = s*256 + t, band = idx >> 9, rem = idx & 511;
        int row = rem >> 3, ch = rem & 7;
        *reinterpret_cast<u16x8*>(&sB[band*4096 + SWZ(row, ch*8)]) = rbr[s];
      }
      __syncthreads();
      if (k0 + 64 < HID) load2(k0 + 64);
#pragma unroll
      for (int kc = 0; kc < 2; ++kc) {
        bf16x8 af[4];
#pragma unroll
        for (int i = 0; i < 4; ++i) {
          int rl = waveM*64 + i*16 + lcol;
          af[i] = *reinterpret_cast<const bf16x8*>(&sA[SWZ(rl, kc*32 + quad*8)]);
        }
#pragma unroll
        for (int b = 0; b < 3; ++b) {
          int ai = (b < 2) ? b : 3;
#pragma unroll
          for (int jj = 0; jj < 2; ++jj) {
            int jl = waveJ*32 + jj*16 + lcol;
            bf16x8 bf = *reinterpret_cast<const bf16x8*>(
                &sB[b*4096 + SWZ(jl, kc*32 + quad*8)]);
#pragma unroll
            for (int i = 0; i < 4; ++i)
              acc[ai][i][jj] = __builtin_amdgcn_mfma_f32_16x16x32_bf16(
                  af[i], bf, acc[ai][i][jj], 0, 0, 0);
          }
        }
      }
    }
  }
  // ---- epilogue: gates -> new_h into d_out hh region ----
#pragma unroll
  for (int i = 0; i < 4; ++i)
#pragma unroll
    for (int jj = 0; jj < 2; ++jj) {
      int j = j0 + waveJ*32 + jj*16 + lcol;
      float br = bs_r[l*HID + j], bz = bs_z[l*HID + j];
      float bi = bn_i[l*HID + j], bh = bn_h[l*HID + j];
#pragma unroll
      for (int g = 0; g < 4; ++g) {
        int r = row0 + waveM*64 + i*16 + quad*4 + g;
        float rg = sigm(acc[0][i][jj][g] + br);
        float zg = sigm(acc[1][i][jj][g] + bz);
        float ng = tanhf(acc[2][i][jj][g] + bi + rg*(acc[3][i][jj][g] + bh));
        float hv = ld1(H, (size_t)r*HID + j, f32);
        st1(outv, 513 + (size_t)r*HID + j, (1.0f - zg)*ng + zg*hv, f32);
      }
    }
}

// ---------------- level means (split-C atomics) ----------------
__global__ void k_lm_acc(const void* __restrict__ outv, const int* __restrict__ dflag,
                         float* __restrict__ lm) {
  const bool f32 = dflag[0] != 0;
  int l = blockIdx.x, cc = blockIdx.y, t = threadIdx.x;
  float s0=0.f, s1=0.f, s2=0.f, s3=0.f;
  for (int c = cc*64; c < cc*64 + 64; ++c) {
    size_t base = 513 + (size_t)(l*CPL + c)*HID;
    s0 += ld1(outv, base + t,       f32);
    s1 += ld1(outv, base + 256 + t, f32);
    s2 += ld1(outv, base + 512 + t, f32);
    s3 += ld1(outv, base + 768 + t, f32);
  }
  atomicAdd(&lm[l*HID + t],       s0);
  atomicAdd(&lm[l*HID + 256 + t], s1);
  atomicAdd(&lm[l*HID + 512 + t], s2);
  atomicAdd(&lm[l*HID + 768 + t], s3);
}
__global__ void k_lmfin(float* __restrict__ lm) {
  int idx = blockIdx.x*256 + threadIdx.x;
  lm[idx] *= (1.0f/1024.0f);
}

// ---------------- predictors (split-K atomics) ----------------
__global__ void k_pz_acc(const float* __restrict__ lm, const void* __restrict__ pW1,
                         const int* __restrict__ dflag, float* __restrict__ pz) {
  const bool f32 = dflag[0] != 0;
  int lv = blockIdx.x, mb = blockIdx.y, kc = blockIdx.z;
  int m = mb*256 + threadIdx.x;
  float acc = 0.0f;
  int i0 = kc*128;
  const float* lmp = lm + (lv + 1)*HID;
  for (int i = i0; i < i0 + 128; ++i)
    acc += lmp[i] * ld1(pW1, ((size_t)lv*HID + i)*HID + m, f32);
  atomicAdd(&pz[lv*HID + m], acc);
}
__global__ void k_pzfin(float* __restrict__ pz, const void* __restrict__ pb1,
                        const int* __restrict__ dflag) {
  const bool f32 = dflag[0] != 0;
  int idx = blockIdx.x*256 + threadIdx.x;   // [0,3072)
  float v = pz[idx] + ld1(pb1, idx, f32);
  pz[idx] = v > 0.0f ? v : 0.0f;
}
__global__ void k_pe_acc(const float* __restrict__ pz, const void* __restrict__ pW2,
                         const int* __restrict__ dflag, float* __restrict__ pe) {
  const bool f32 = dflag[0] != 0;
  int lv = blockIdx.x, ob = blockIdx.y, kc = blockIdx.z;
  int o = ob*256 + threadIdx.x;
  float acc = 0.0f;
  int m0 = kc*128;
  const float* pzp = pz + lv*HID;
  for (int m = m0; m < m0 + 128; ++m)
    acc += pzp[m] * ld1(pW2, ((size_t)lv*HID + m)*HID + o, f32);
  atomicAdd(&pe[lv*HID + o], acc);
}
__global__ void k_pefin(float* __restrict__ pe, const void* __restrict__ pb2,
                        const float* __restrict__ lm, const int* __restrict__ dflag) {
  const bool f32 = dflag[0] != 0;
  int idx = blockIdx.x*256 + threadIdx.x;   // [0,3072)
  pe[idx] = (pe[idx] + ld1(pb2, idx, f32) - lm[idx]) * 0.05f;
}

__global__ void k_addc_gop(const float* __restrict__ lm, const float* __restrict__ pe,
                           float* __restrict__ addc, float* __restrict__ gop) {
  int j = blockIdx.x*256 + threadIdx.x;
  float pe0 = pe[j], pe1 = pe[1024 + j], pe2 = pe[2048 + j];
  float d0 = pe0, d1 = pe1 - 0.5f*pe0, d2 = pe2 - 0.5f*pe1, d3 = -0.5f*pe2;
  float l0 = lm[j], l1 = lm[1024 + j], l2 = lm[2048 + j], l3 = lm[3072 + j];
  addc[j]        = 0.2775f*l0 + d0;
  addc[1024 + j] = 0.2775f*l1 + d1;
  addc[2048 + j] = 0.2775f*l2 + d2;
  addc[3072 + j] = 0.2775f*l3 + d3;
  gop[j] = 0.25f*((l0 + d0) + (l1 + d1) + (l2 + d2) + (l3 + d3));
}

__global__ void k_comb_acc(const float* __restrict__ lm, const void* __restrict__ peiW,
                           const int* __restrict__ dflag, float* __restrict__ comb) {
  const bool f32 = dflag[0] != 0;
  int ob = blockIdx.x, kc = blockIdx.y;
  int o = ob*256 + threadIdx.x;
  float acc = 0.0f;
  int i0 = kc*256;
  for (int i = i0; i < i0 + 256; ++i)
    acc += lm[i] * ld1(peiW, (size_t)i*OUTD + o, f32);
  atomicAdd(&comb[o], acc);
}
__global__ void k_fin(const float* __restrict__ comb, const void* __restrict__ peib,
                      const float* __restrict__ tsum, const int* __restrict__ dflag,
                      void* __restrict__ outv) {
  const bool f32 = dflag[0] != 0;
  int o = blockIdx.x*256 + threadIdx.x;
  st1(outv, o, comb[o] + ld1(peib, o, f32), f32);
  if (o == 0) st1(outv, 512, tsum[0] * (1.0f/(4096.0f*512.0f)), f32);
}

__global__ void k_hh(void* __restrict__ outv, const float* __restrict__ addc,
                     const float* __restrict__ gop, const int* __restrict__ step,
                     const int* __restrict__ dflag) {
  const bool f32 = dflag[0] != 0;
  int row = blockIdx.x, t = threadIdx.x;
  int l = row >> 10, c = row & 1023;
  bool debate = (step[0] > 5) && (c < 256);
  size_t base = 513 + (size_t)row*HID;
#pragma unroll
  for (int k = 0; k < 4; ++k) {
    int j = t + k*256;
    float v = 0.7225f * ld1(outv, base + j, f32) + addc[l*HID + j];
    if (debate) v = 0.85f*v + 0.15f*gop[j];
    st1(outv, base + j, v, f32);
  }
}

extern "C" void kernel_launch(void* const* d_in, const int* in_sizes, int n_in,
                              void* d_out, int out_size, void* d_ws, size_t ws_size,
                              hipStream_t stream) {
  (void)in_sizes; (void)n_in; (void)out_size; (void)ws_size;
  const void* x    = d_in[0];
  const void* hid  = d_in[1];
  const void* eaW1 = d_in[2];
  const void* eab1 = d_in[3];
  const void* eaW2 = d_in[4];
  const void* eab2 = d_in[5];
  const void* egW1 = d_in[6];
  const void* egb1 = d_in[7];
  const void* egW2 = d_in[8];
  const void* egb2 = d_in[9];
  const void* gWih = d_in[10];
  const void* gWhh = d_in[11];
  const void* gbih = d_in[12];
  const void* gbhh = d_in[13];
  const void* pW1  = d_in[14];
  const void* pb1  = d_in[15];
  const void* pW2  = d_in[16];
  const void* pb2  = d_in[17];
  const void* peiW = d_in[18];
  const void* peib = d_in[19];
  const int*  step = (const int*)d_in[20];

  // ---- workspace layout (~20.06 MB, proven size) ----
  float* wsf = (float*)d_ws;
  float* tsum    = wsf + 0;       // 64
  float* baseacc = wsf + 64;      // 1024
  float* lm      = wsf + 1088;    // 4096
  float* pz      = wsf + 5184;    // 3072
  float* pe      = wsf + 8256;    // 3072
  float* comb    = wsf + 11328;   // 512 (+pad to 12288)
  int*   dflag   = (int*)(wsf + 12288);  // 64
  float* bs_r    = wsf + 12352;   // 4096
  float* bs_z    = wsf + 16448;   // 4096
  float* bn_i    = wsf + 20544;   // 4096
  float* bn_h    = wsf + 24640;   // 4096
  float* addc    = wsf + 28736;   // 4096
  float* gop     = wsf + 32832;   // 1024
  u16* Zb   = (u16*)(wsf + 33856);        // 4096*256
  u16* OUTT = Zb + (size_t)4096*256;      // 4096*544
  u16* WihP = OUTT + (size_t)4096*KP;     // 12288*544
  // W1T (4*256*1024 u16 = 2.1 MB) overlays OUTT: dead once k_z finishes,
  // before k_out writes OUTT.
  u16* W1T  = OUTT;

  k_detect   <<<dim3(1),        dim3(256), 0, stream>>>(x, dflag);
  k_prep     <<<dim3(64),       dim3(256), 0, stream>>>(wsf, gbih, gbhh, dflag,
                                                        bs_r, bs_z, bn_i, bn_h);
  k_prep_wih <<<dim3(12288),    dim3(256), 0, stream>>>(gWih, dflag, WihP);
  k_prep_w1t <<<dim3(4,2,8),    dim3(256), 0, stream>>>(eaW1, egW1, dflag, W1T);
  k_base_acc <<<dim3(4,2,4),    dim3(128), 0, stream>>>(x, eaW1, egW1, dflag, baseacc);
  k_z_mfma   <<<dim3(64,4),     dim3(256), 0, stream>>>(hid, W1T, eab1, egb1,
                                                        baseacc, dflag, Zb);
  k_out      <<<dim3(64,8),     dim3(256), 0, stream>>>(Zb, eaW2, egW2, eab2, egb2,
                                                        dflag, OUTT);
  k_tension  <<<dim3(4096),     dim3(256), 0, stream>>>(OUTT, tsum);
  k_gru_mfma <<<dim3(512),      dim3(256), 0, stream>>>(OUTT, hid, WihP, gWhh,
                                                        bs_r, bs_z, bn_i, bn_h,
                                                        dflag, d_out);
  k_lm_acc   <<<dim3(4,16),     dim3(256), 0, stream>>>(d_out, dflag, lm);
  k_lmfin    <<<dim3(16),       dim3(256), 0, stream>>>(lm);
  k_pz_acc   <<<dim3(3,4,8),    dim3(256), 0, stream>>>(lm, pW1, dflag, pz);
  k_pzfin    <<<dim3(12),       dim3(256), 0, stream>>>(pz, pb1, dflag);
  k_pe_acc   <<<dim3(3,4,8),    dim3(256), 0, stream>>>(pz, pW2, dflag, pe);
  k_pefin    <<<dim3(12),       dim3(256), 0, stream>>>(pe, pb2, lm, dflag);
  k_addc_gop <<<dim3(4),        dim3(256), 0, stream>>>(lm, pe, addc, gop);
  k_comb_acc <<<dim3(2,16),     dim3(256), 0, stream>>>(lm, peiW, dflag, comb);
  k_fin      <<<dim3(2),        dim3(256), 0, stream>>>(comb, peib, tsum, dflag, d_out);
  k_hh       <<<dim3(4096),     dim3(256), 0, stream>>>(d_out, addc, gop, step, dflag);
}

// Round 2
// 596.485 us; speedup vs baseline: 1.1217x; 1.0035x over previous
//
#include <hip/hip_runtime.h>
#include <math.h>

// Problem constants
#define L4   4
#define CPL  1024
#define HID  1024
#define IND  512
#define MLPD 128
#define OUTD 512
#define G3   3072
#define ROWS 4096   // L4*CPL
#define KP   544    // padded gi K: 512 OUT + 1 tension + 31 zeros

typedef unsigned short u16;
typedef u16   u16x8  __attribute__((ext_vector_type(8)));
typedef short bf16x8 __attribute__((ext_vector_type(8)));
typedef float f32x4  __attribute__((ext_vector_type(4)));

__device__ __forceinline__ float b2f(u16 u) {
  return __uint_as_float(((unsigned int)u) << 16);
}
__device__ __forceinline__ u16 f2b(float f) {   // round-to-nearest-even
  unsigned int x = __float_as_uint(f);
  x += 0x7fffu + ((x >> 16) & 1u);
  return (u16)(x >> 16);
}
__device__ __forceinline__ float sigm(float v) { return 1.0f/(1.0f + expf(-v)); }

// ---- dual-dtype access helpers: f32 flag selects float32 vs bf16 layout ----
struct F4 { float x, y, z, w; };
__device__ __forceinline__ F4 ld4(const void* p, size_t i, bool f32) {
  F4 r;
  if (f32) {
    float4 v = *reinterpret_cast<const float4*>((const float*)p + i);
    r.x = v.x; r.y = v.y; r.z = v.z; r.w = v.w;
  } else {
    ushort4 v = *reinterpret_cast<const ushort4*>((const u16*)p + i);
    r.x = b2f(v.x); r.y = b2f(v.y); r.z = b2f(v.z); r.w = b2f(v.w);
  }
  return r;
}
__device__ __forceinline__ float ld1(const void* p, size_t i, bool f32) {
  return f32 ? ((const float*)p)[i] : b2f(((const u16*)p)[i]);
}
__device__ __forceinline__ void st1(void* p, size_t i, float v, bool f32) {
  if (f32) ((float*)p)[i] = v; else ((u16*)p)[i] = f2b(v);
}
// load 8 elems -> bf16 bits (converting if fp32). i must be multiple of 8.
__device__ __forceinline__ u16x8 ldc8(const void* p, size_t i, bool f32) {
  u16x8 r;
  if (f32) {
    const float* q = (const float*)p + i;
    float4 v0 = *reinterpret_cast<const float4*>(q);
    float4 v1 = *reinterpret_cast<const float4*>(q + 4);
    r[0]=f2b(v0.x); r[1]=f2b(v0.y); r[2]=f2b(v0.z); r[3]=f2b(v0.w);
    r[4]=f2b(v1.x); r[5]=f2b(v1.y); r[6]=f2b(v1.z); r[7]=f2b(v1.w);
  } else {
    r = *reinterpret_cast<const u16x8*>((const u16*)p + i);
  }
  return r;
}

// ---------------- dtype detector ----------------
__global__ void k_detect(const void* __restrict__ x, int* __restrict__ flag) {
  int t = threadIdx.x;   // 256
  const u16* xu = (const u16*)x;
  unsigned u = xu[2*t];
  int e = (u >> 7) & 0xFF;
  int good = (e >= 96 && e <= 134) ? 1 : 0;
  __shared__ int cnt[256];
  cnt[t] = good;
  __syncthreads();
  for (int s = 128; s > 0; s >>= 1) { if (t < s) cnt[t] += cnt[t+s]; __syncthreads(); }
  if (t == 0) flag[0] = (cnt[0] < 200) ? 1 : 0;   // 1 = float32, 0 = bf16
}

// ---------------- prep: zero accumulators + bias sums ----------------
__global__ void k_prep(float* __restrict__ zf, const void* __restrict__ bih,
                       const void* __restrict__ bhh, const int* __restrict__ dflag,
                       float* __restrict__ bs_r, float* __restrict__ bs_z,
                       float* __restrict__ bn_i, float* __restrict__ bn_h) {
  const bool f32 = dflag[0] != 0;
  int b = blockIdx.x, t = threadIdx.x;
  if (b < 16) {
    int idx = b*256 + t;          // [0,4096)
    int l = idx >> 10, j = idx & 1023;
    bs_r[idx] = ld1(bih, l*G3 + j, f32)        + ld1(bhh, l*G3 + j, f32);
    bs_z[idx] = ld1(bih, l*G3 + 1024 + j, f32) + ld1(bhh, l*G3 + 1024 + j, f32);
    bn_i[idx] = ld1(bih, l*G3 + 2048 + j, f32);
    bn_h[idx] = ld1(bhh, l*G3 + 2048 + j, f32);
  } else {
    int idx = (b-16)*256 + t;     // [0,12288)
    zf[idx] = 0.0f;
  }
}

// ---------------- repack Wih -> bf16 [4][3072][544] (col 512 = tension wt) ----
__global__ void k_prep_wih(const void* __restrict__ Wih, const int* __restrict__ dflag,
                           u16* __restrict__ WihP) {
  const bool f32 = dflag[0] != 0;
  int row = blockIdx.x;            // 0..12287 == l*3072+g
  int t = threadIdx.x;
  size_t src = (size_t)row * 513;
  size_t dst = (size_t)row * KP;
  WihP[dst + t]       = f2b(ld1(Wih, src + t, f32));
  WihP[dst + 256 + t] = f2b(ld1(Wih, src + 256 + t, f32));
  if (t < 32) {
    float v = (t == 0) ? ld1(Wih, src + 512, f32) : 0.0f;
    WihP[dst + 512 + t] = f2b(v);
  }
}

// ---------------- repack W1 hidden part -> bf16 transposed W1T[l][path*128+m][k] ----
// src: W1[l][512+k][m]  (k in [0,1024), m in [0,128))
__global__ void k_prep_w1t(const void* __restrict__ eaW1, const void* __restrict__ egW1,
                           const int* __restrict__ dflag, u16* __restrict__ W1T) {
  const bool f32 = dflag[0] != 0;
  __shared__ u16 sT[128*130];
  int l = blockIdx.x, path = blockIdx.y, kt = blockIdx.z;   // (4,2,8)
  int t = threadIdx.x;
  const void* W1 = path ? egW1 : eaW1;
  // read 128 k-rows x 128 m (coalesced over m), store transposed in LDS
  for (int rr = 0; rr < 128; rr += 2) {
    int r = rr + (t >> 7), m = t & 127;
    float v = ld1(W1, ((size_t)l*1536 + 512 + kt*128 + r)*MLPD + m, f32);
    sT[m*130 + r] = f2b(v);
  }
  __syncthreads();
  // write rows of W1T (coalesced over k)
  for (int mm = 0; mm < 128; mm += 2) {
    int m = mm + (t >> 7), kk = t & 127;
    W1T[((size_t)l*256 + path*128 + m)*1024 + kt*128 + kk] = sT[m*130 + kk];
  }
}

// ---------------- base accumulation (x part of encoder layer 1) ----------------
__global__ void k_base_acc(const void* __restrict__ x, const void* __restrict__ eaW1,
                           const void* __restrict__ egW1, const int* __restrict__ dflag,
                           float* __restrict__ baseacc) {
  const bool f32 = dflag[0] != 0;
  int l = blockIdx.x, path = blockIdx.y, kc = blockIdx.z, m = threadIdx.x; // 128 thr
  const void* W1 = path ? egW1 : eaW1;
  float acc = 0.0f;
  int i0 = kc*128;
  for (int i = i0; i < i0 + 128; ++i)
    acc += ld1(x, i, f32) * ld1(W1, ((size_t)l*1536 + i)*MLPD + m, f32);
  atomicAdd(&baseacc[path*512 + l*MLPD + m], acc);
}

// ---------------- MFMA k_z: Z = relu(base + b1 + H @ W1T^T) ----------------
// A = H [4096,1024] (dual), B = W1T [l][256][1024] bf16 (NT). Tile 64x64, 4 waves 2x2.
// v2: double-buffered LDS, ONE raw barrier per K-step, prefetch in flight across
// barriers (reg staging -> no vmcnt drain at barrier).
#define LPAD 40
__global__ __launch_bounds__(256) void k_z_mfma(
    const void* __restrict__ H, const u16* __restrict__ W1T,
    const void* __restrict__ eab1, const void* __restrict__ egb1,
    const float* __restrict__ baseacc, const int* __restrict__ dflag,
    u16* __restrict__ Z) {
  const bool f32 = dflag[0] != 0;
  __shared__ u16 sA[2][64*LPAD];
  __shared__ u16 sB[2][64*LPAD];
  int t = threadIdx.x;
  int row0 = blockIdx.x * 64;
  int n0   = blockIdx.y * 64;          // 0,64,128,192
  int l    = row0 >> 10;
  int wid = t >> 6, lane = t & 63;
  int waveM = wid >> 1, waveN = wid & 1;
  int quad = lane >> 4, lcol = lane & 15;
  int arow = t >> 2, kq = (t & 3) * 8;

  f32x4 acc[2][2];
  const f32x4 zz = {0.0f,0.0f,0.0f,0.0f};
#pragma unroll
  for (int i = 0; i < 2; ++i)
#pragma unroll
    for (int j = 0; j < 2; ++j) acc[i][j] = zz;

  size_t habase = (size_t)(row0 + arow)*HID;
  const u16* Bb = W1T + ((size_t)l*256 + n0 + arow)*1024;

  u16x8 av = ldc8(H, habase + kq, f32);
  u16x8 bv = *reinterpret_cast<const u16x8*>(Bb + kq);
  int cur = 0;
  for (int k0 = 0; k0 < HID; k0 += 32) {
    *reinterpret_cast<u16x8*>(&sA[cur][arow*LPAD + kq]) = av;
    *reinterpret_cast<u16x8*>(&sB[cur][arow*LPAD + kq]) = bv;
    asm volatile("s_waitcnt lgkmcnt(0)" ::: "memory");
    __builtin_amdgcn_s_barrier();
    if (k0 + 32 < HID) {
      av = ldc8(H, habase + k0 + 32 + kq, f32);
      bv = *reinterpret_cast<const u16x8*>(Bb + k0 + 32 + kq);
    }
    bf16x8 af[2];
#pragma unroll
    for (int i = 0; i < 2; ++i)
      af[i] = *reinterpret_cast<const bf16x8*>(&sA[cur][(waveM*32 + i*16 + lcol)*LPAD + quad*8]);
#pragma unroll
    for (int j = 0; j < 2; ++j) {
      bf16x8 bf = *reinterpret_cast<const bf16x8*>(&sB[cur][(waveN*32 + j*16 + lcol)*LPAD + quad*8]);
#pragma unroll
      for (int i = 0; i < 2; ++i)
        acc[i][j] = __builtin_amdgcn_mfma_f32_16x16x32_bf16(af[i], bf, acc[i][j], 0, 0, 0);
    }
    cur ^= 1;
  }
  // epilogue: + base + b1, relu, store
#pragma unroll
  for (int j = 0; j < 2; ++j) {
    int nn = n0 + waveN*32 + j*16 + lcol;
    int path = nn >> 7, m = nn & 127;
    float bval = baseacc[path*512 + l*MLPD + m] +
                 ld1(path ? egb1 : eab1, l*MLPD + m, f32);
#pragma unroll
    for (int i = 0; i < 2; ++i)
#pragma unroll
      for (int g = 0; g < 4; ++g) {
        int r = row0 + waveM*32 + i*16 + quad*4 + g;
        float v = acc[i][j][g] + bval;
        Z[(size_t)r*256 + nn] = f2b(v > 0.0f ? v : 0.0f);
      }
  }
}

// ---------------- VALU k_out (small): OUT = Za@W2a - Zg@W2g + bias diff ----------------
#define BM 64
#define BN 64
#define BK 16
__global__ __launch_bounds__(256) void k_out(
    const u16* __restrict__ Zb, const void* __restrict__ eaW2, const void* __restrict__ egW2,
    const void* __restrict__ eab2, const void* __restrict__ egb2,
    const int* __restrict__ dflag, u16* __restrict__ OUTT) {
  const bool f32 = dflag[0] != 0;
  __shared__ float As[BK][BM];
  __shared__ float Bs[BK][BN];
  int t = threadIdx.x;
  int row0 = blockIdx.x * BM;
  int n0   = blockIdx.y * BN;          // 0..448
  int l    = row0 >> 10;
  const u16* Ab = Zb + (size_t)row0 * 256;
  int tx = t & 15, ty = t >> 4;
  int am = t >> 2, akq = (t & 3) * 4;
  int bk = t >> 4, bn = (t & 15) * 4;

  float acc[4][4];
#pragma unroll
  for (int j = 0; j < 4; ++j) {
    int o = n0 + tx*4 + j;
    float bd = ld1(eab2, l*OUTD + o, f32) - ld1(egb2, l*OUTD + o, f32);
#pragma unroll
    for (int i = 0; i < 4; ++i) acc[i][j] = bd;
  }
  for (int ph = 0; ph < 2; ++ph) {
    const void* B = ph ? egW2 : eaW2;
    size_t boff = (size_t)l*MLPD*OUTD + n0;
    float sgn = ph ? -1.0f : 1.0f;
    for (int k0 = 0; k0 < MLPD; k0 += BK) {
      ushort4 avu = *reinterpret_cast<const ushort4*>(Ab + (size_t)am*256 + ph*128 + k0 + akq);
      F4 bvf = ld4(B, boff + (size_t)(k0 + bk)*OUTD + bn, f32);
      __syncthreads();
      As[akq+0][am] = b2f(avu.x); As[akq+1][am] = b2f(avu.y);
      As[akq+2][am] = b2f(avu.z); As[akq+3][am] = b2f(avu.w);
      Bs[bk][bn+0] = sgn*bvf.x; Bs[bk][bn+1] = sgn*bvf.y;
      Bs[bk][bn+2] = sgn*bvf.z; Bs[bk][bn+3] = sgn*bvf.w;
      __syncthreads();
#pragma unroll
      for (int kk = 0; kk < BK; ++kk) {
        float4 a4 = *reinterpret_cast<const float4*>(&As[kk][ty*4]);
        float4 b4 = *reinterpret_cast<const float4*>(&Bs[kk][tx*4]);
        float a[4] = {a4.x,a4.y,a4.z,a4.w};
        float b[4] = {b4.x,b4.y,b4.z,b4.w};
#pragma unroll
        for (int i = 0; i < 4; ++i)
#pragma unroll
          for (int j = 0; j < 4; ++j) acc[i][j] += a[i]*b[j];
      }
    }
  }
#pragma unroll
  for (int i = 0; i < 4; ++i) {
    int r = row0 + ty*4 + i;
#pragma unroll
    for (int j = 0; j < 4; ++j)
      OUTT[(size_t)r*KP + n0 + tx*4 + j] = f2b(acc[i][j]);
  }
}

// tension -> OUTT col 512 (bf16); zero pad cols 513..543; tsum += sumsq(row)
__global__ void k_tension(u16* __restrict__ OUTT, float* __restrict__ tsum) {
  int row = blockIdx.x, t = threadIdx.x;
  u16* p = OUTT + (size_t)row*KP;
  float v0 = b2f(p[t]), v1 = b2f(p[t+256]);
  float s = v0*v0 + v1*v1;
#pragma unroll
  for (int off = 32; off > 0; off >>= 1) s += __shfl_down(s, off, 64);
  __shared__ float red[4];
  if ((t & 63) == 0) red[t >> 6] = s;
  __syncthreads();
  if (t == 0) {
    float tot = red[0] + red[1] + red[2] + red[3];
    p[512] = f2b(tot * (1.0f/512.0f));
    atomicAdd(tsum, tot);
  }
  if (t < 31) p[513 + t] = 0;
}

// ---------------- fused MFMA GRU v3: dbuf LDS, 1 raw barrier/K-step ----
// Per block: 128 rows x 64 j-cols x {r,z,n} bands. 4 waves, each 64x32.
// T3-minimum schedule: stage(buf[cur]) -> lgkmcnt(0) -> raw s_barrier ->
// issue prefetch(t+1) -> MFMA(buf[cur]). Register staging means vmcnt is
// NEVER drained at a barrier: global loads stay in flight (counted vmcnt
// inserted by compiler at the next stage()'s reg use). Pipeline stays full
// across the GEMM1->GEMM2 boundary (bridge prefetch).
#define SWZ(row, ku) ((row)*64 + ((ku) ^ (((row)&7)<<3)))
__global__ __launch_bounds__(256, 2) void k_gru_mfma(
    const u16* __restrict__ OUTT, const void* __restrict__ H,
    const u16* __restrict__ WihP, const void* __restrict__ Whh,
    const float* __restrict__ bs_r, const float* __restrict__ bs_z,
    const float* __restrict__ bn_i, const float* __restrict__ bn_h,
    const int* __restrict__ dflag, void* __restrict__ outv) {
  const bool f32 = dflag[0] != 0;
  __shared__ __align__(16) u16 sA[2][128*64];     // 32 KB
  __shared__ __align__(16) u16 sB[2][3*64*64];    // 48 KB  (80 KB total, 2 blk/CU)
  int t = threadIdx.x;
  // XCD swizzle (512 blocks, 512%8==0 -> bijective): xg = XCD id.
  // Each XCD owns one (level, j-half): B panel stays L2-local.
  int bid = blockIdx.x;
  int xg = bid & 7, inner = bid >> 3;      // inner 0..63
  int l = xg & 3, jG = xg >> 2;
  int rbi = inner & 7, jbl = inner >> 3;   // 8 row-blocks, 8 j-blocks
  int row0 = (l*8 + rbi) * 128;
  int j0   = (jG*8 + jbl) * 64;
  int wid = t >> 6, lane = t & 63;
  int waveM = wid & 1, waveJ = wid >> 1;   // 2x2 waves over 128x64
  int quad = lane >> 4, lcol = lane & 15;

  f32x4 acc[4][4][2];   // band {r,z,i_n,h_n} x 4 m-frags x 2 j-frags
  const f32x4 zz = {0.0f,0.0f,0.0f,0.0f};
#pragma unroll
  for (int b = 0; b < 4; ++b)
#pragma unroll
    for (int i = 0; i < 4; ++i)
#pragma unroll
      for (int j = 0; j < 2; ++j) acc[b][i][j] = zz;

  // staging decomposition (per thread): A: 4 chunks, B: 6 chunks of u16x8.
  // idx = s*256+t;  A: row=idx>>3 (0..127), ch=idx&7;  B: band=idx>>9,
  // row=(idx&511)>>3 (0..63), ch=idx&7.  8 threads/row -> 128 B coalesced.
  u16x8 ra[4], rbr[6];
  auto load1 = [&](int k0) {           // GEMM1 sources (zero-pad K tail)
    int kw = KP - k0;                  // 64 except last step (32)
#pragma unroll
    for (int s = 0; s < 4; ++s) {
      int idx = s*256 + t, row = idx >> 3, ch = idx & 7;
      if (ch*8 < kw)
        ra[s] = *reinterpret_cast<const u16x8*>(
            OUTT + (size_t)(row0 + row)*KP + k0 + ch*8);
      else { u16x8 z = {0,0,0,0,0,0,0,0}; ra[s] = z; }
    }
#pragma unroll
    for (int s = 0; s < 6; ++s) {
      int idx = s*256 + t, band = idx >> 9, rem = idx & 511;
      int row = rem >> 3, ch = rem & 7;
      if (ch*8 < kw)
        rbr[s] = *reinterpret_cast<const u16x8*>(
            WihP + ((size_t)l*G3 + band*1024 + j0 + row)*KP + k0 + ch*8);
      else { u16x8 z = {0,0,0,0,0,0,0,0}; rbr[s] = z; }
    }
  };
  auto load2 = [&](int k0) {           // GEMM2 sources (dual-dtype)
#pragma unroll
    for (int s = 0; s < 4; ++s) {
      int idx = s*256 + t, row = idx >> 3, ch = idx & 7;
      ra[s] = ldc8(H, (size_t)(row0 + row)*HID + k0 + ch*8, f32);
    }
#pragma unroll
    for (int s = 0; s < 6; ++s) {
      int idx = s*256 + t, band = idx >> 9, rem = idx & 511;
      int row = rem >> 3, ch = rem & 7;
      rbr[s] = ldc8(Whh, ((size_t)l*G3 + band*1024 + j0 + row)*HID + k0 + ch*8, f32);
    }
  };
  auto stage = [&](int cb) {
#pragma unroll
    for (int s = 0; s < 4; ++s) {
      int idx = s*256 + t, row = idx >> 3, ch = idx & 7;
      *reinterpret_cast<u16x8*>(&sA[cb][SWZ(row, ch*8)]) = ra[s];
    }
#pragma unroll
    for (int s = 0; s < 6; ++s) {
      int idx = s*256 + t, band = idx >> 9, rem = idx & 511;
      int row = rem >> 3, ch = rem & 7;
      *reinterpret_cast<u16x8*>(&sB[cb][band*4096 + SWZ(row, ch*8)]) = rbr[s];
    }
  };

  int cur = 0;
  // ---- GEMM1: gi over K=544 (pure bf16; tail zero-padded -> no predicates) ----
  load1(0);
  for (int k0 = 0; k0 < KP; k0 += 64) {
    stage(cur);
    asm volatile("s_waitcnt lgkmcnt(0)" ::: "memory");
    __builtin_amdgcn_s_barrier();
    if (k0 + 64 < KP) load1(k0 + 64);
    else              load2(0);               // bridge into GEMM2
    __builtin_amdgcn_s_setprio(1);
#pragma unroll
    for (int kc = 0; kc < 2; ++kc) {
      bf16x8 af[4];
#pragma unroll
      for (int i = 0; i < 4; ++i) {
        int rl = waveM*64 + i*16 + lcol;
        af[i] = *reinterpret_cast<const bf16x8*>(&sA[cur][SWZ(rl, kc*32 + quad*8)]);
      }
#pragma unroll
      for (int b = 0; b < 3; ++b)
#pragma unroll
        for (int jj = 0; jj < 2; ++jj) {
          int jl = waveJ*32 + jj*16 + lcol;
          bf16x8 bf = *reinterpret_cast<const bf16x8*>(
              &sB[cur][b*4096 + SWZ(jl, kc*32 + quad*8)]);
#pragma unroll
          for (int i = 0; i < 4; ++i)
            acc[b][i][jj] = __builtin_amdgcn_mfma_f32_16x16x32_bf16(
                af[i], bf, acc[b][i][jj], 0, 0, 0);
        }
    }
    __builtin_amdgcn_s_setprio(0);
    cur ^= 1;
  }
  // ---- GEMM2: gh over K=1024 (dual-dtype converted on stage) ----
  for (int k0 = 0; k0 < HID; k0 += 64) {
    stage(cur);
    asm volatile("s_waitcnt lgkmcnt(0)" ::: "memory");
    __builtin_amdgcn_s_barrier();
    if (k0 + 64 < HID) load2(k0 + 64);
    __builtin_amdgcn_s_setprio(1);
#pragma unroll
    for (int kc = 0; kc < 2; ++kc) {
      bf16x8 af[4];
#pragma unroll
      for (int i = 0; i < 4; ++i) {
        int rl = waveM*64 + i*16 + lcol;
        af[i] = *reinterpret_cast<const bf16x8*>(&sA[cur][SWZ(rl, kc*32 + quad*8)]);
      }
#pragma unroll
      for (int b = 0; b < 3; ++b) {
        int ai = (b < 2) ? b : 3;
#pragma unroll
        for (int jj = 0; jj < 2; ++jj) {
          int jl = waveJ*32 + jj*16 + lcol;
          bf16x8 bf = *reinterpret_cast<const bf16x8*>(
              &sB[cur][b*4096 + SWZ(jl, kc*32 + quad*8)]);
#pragma unroll
          for (int i = 0; i < 4; ++i)
            acc[ai][i][jj] = __builtin_amdgcn_mfma_f32_16x16x32_bf16(
                af[i], bf, acc[ai][i][jj], 0, 0, 0);
        }
      }
    }
    __builtin_amdgcn_s_setprio(0);
    cur ^= 1;
  }
  // ---- epilogue: gates -> new_h into d_out hh region ----
#pragma unroll
  for (int i = 0; i < 4; ++i)
#pragma unroll
    for (int jj = 0; jj < 2; ++jj) {
      int j = j0 + waveJ*32 + jj*16 + lcol;
      float br = bs_r[l*HID + j], bz = bs_z[l*HID + j];
      float bi = bn_i[l*HID + j], bh = bn_h[l*HID + j];
#pragma unroll
      for (int g = 0; g < 4; ++g) {
        int r = row0 + waveM*64 + i*16 + quad*4 + g;
        float rg = sigm(acc[0][i][jj][g] + br);
        float zg = sigm(acc[1][i][jj][g] + bz);
        float ng = tanhf(acc[2][i][jj][g] + bi + rg*(acc[3][i][jj][g] + bh));
        float hv = ld1(H, (size_t)r*HID + j, f32);
        st1(outv, 513 + (size_t)r*HID + j, (1.0f - zg)*ng + zg*hv, f32);
      }
    }
}

// ---------------- level means (split-C atomics) ----------------
__global__ void k_lm_acc(const void* __restrict__ outv, const int* __restrict__ dflag,
                         float* __restrict__ lm) {
  const bool f32 = dflag[0] != 0;
  int l = blockIdx.x, cc = blockIdx.y, t = threadIdx.x;
  float s0=0.f, s1=0.f, s2=0.f, s3=0.f;
  for (int c = cc*64; c < cc*64 + 64; ++c) {
    size_t base = 513 + (size_t)(l*CPL + c)*HID;
    s0 += ld1(outv, base + t,       f32);
    s1 += ld1(outv, base + 256 + t, f32);
    s2 += ld1(outv, base + 512 + t, f32);
    s3 += ld1(outv, base + 768 + t, f32);
  }
  atomicAdd(&lm[l*HID + t],       s0);
  atomicAdd(&lm[l*HID + 256 + t], s1);
  atomicAdd(&lm[l*HID + 512 + t], s2);
  atomicAdd(&lm[l*HID + 768 + t], s3);
}
__global__ void k_lmfin(float* __restrict__ lm) {
  int idx = blockIdx.x*256 + threadIdx.x;
  lm[idx] *= (1.0f/1024.0f);
}

// ---------------- predictors (split-K atomics) ----------------
__global__ void k_pz_acc(const float* __restrict__ lm, const void* __restrict__ pW1,
                         const int* __restrict__ dflag, float* __restrict__ pz) {
  const bool f32 = dflag[0] != 0;
  int lv = blockIdx.x, mb = blockIdx.y, kc = blockIdx.z;
  int m = mb*256 + threadIdx.x;
  float acc = 0.0f;
  int i0 = kc*128;
  const float* lmp = lm + (lv + 1)*HID;
  for (int i = i0; i < i0 + 128; ++i)
    acc += lmp[i] * ld1(pW1, ((size_t)lv*HID + i)*HID + m, f32);
  atomicAdd(&pz[lv*HID + m], acc);
}
__global__ void k_pzfin(float* __restrict__ pz, const void* __restrict__ pb1,
                        const int* __restrict__ dflag) {
  const bool f32 = dflag[0] != 0;
  int idx = blockIdx.x*256 + threadIdx.x;   // [0,3072)
  float v = pz[idx] + ld1(pb1, idx, f32);
  pz[idx] = v > 0.0f ? v : 0.0f;
}
__global__ void k_pe_acc(const float* __restrict__ pz, const void* __restrict__ pW2,
                         const int* __restrict__ dflag, float* __restrict__ pe) {
  const bool f32 = dflag[0] != 0;
  int lv = blockIdx.x, ob = blockIdx.y, kc = blockIdx.z;
  int o = ob*256 + threadIdx.x;
  float acc = 0.0f;
  int m0 = kc*128;
  const float* pzp = pz + lv*HID;
  for (int m = m0; m < m0 + 128; ++m)
    acc += pzp[m] * ld1(pW2, ((size_t)lv*HID + m)*HID + o, f32);
  atomicAdd(&pe[lv*HID + o], acc);
}
__global__ void k_pefin(float* __restrict__ pe, const void* __restrict__ pb2,
                        const float* __restrict__ lm, const int* __restrict__ dflag) {
  const bool f32 = dflag[0] != 0;
  int idx = blockIdx.x*256 + threadIdx.x;   // [0,3072)
  pe[idx] = (pe[idx] + ld1(pb2, idx, f32) - lm[idx]) * 0.05f;
}

__global__ void k_addc_gop(const float* __restrict__ lm, const float* __restrict__ pe,
                           float* __restrict__ addc, float* __restrict__ gop) {
  int j = blockIdx.x*256 + threadIdx.x;
  float pe0 = pe[j], pe1 = pe[1024 + j], pe2 = pe[2048 + j];
  float d0 = pe0, d1 = pe1 - 0.5f*pe0, d2 = pe2 - 0.5f*pe1, d3 = -0.5f*pe2;
  float l0 = lm[j], l1 = lm[1024 + j], l2 = lm[2048 + j], l3 = lm[3072 + j];
  addc[j]        = 0.2775f*l0 + d0;
  addc[1024 + j] = 0.2775f*l1 + d1;
  addc[2048 + j] = 0.2775f*l2 + d2;
  addc[3072 + j] = 0.2775f*l3 + d3;
  gop[j] = 0.25f*((l0 + d0) + (l1 + d1) + (l2 + d2) + (l3 + d3));
}

__global__ void k_comb_acc(const float* __restrict__ lm, const void* __restrict__ peiW,
                           const int* __restrict__ dflag, float* __restrict__ comb) {
  const bool f32 = dflag[0] != 0;
  int ob = blockIdx.x, kc = blockIdx.y;
  int o = ob*256 + threadIdx.x;
  float acc = 0.0f;
  int i0 = kc*256;
  for (int i = i0; i < i0 + 256; ++i)
    acc += lm[i] * ld1(peiW, (size_t)i*OUTD + o, f32);
  atomicAdd(&comb[o], acc);
}
__global__ void k_fin(const float* __restrict__ comb, const void* __restrict__ peib,
                      const float* __restrict__ tsum, const int* __restrict__ dflag,
                      void* __restrict__ outv) {
  const bool f32 = dflag[0] != 0;
  int o = blockIdx.x*256 + threadIdx.x;
  st1(outv, o, comb[o] + ld1(peib, o, f32), f32);
  if (o == 0) st1(outv, 512, tsum[0] * (1.0f/(4096.0f*512.0f)), f32);
}

__global__ void k_hh(void* __restrict__ outv, const float* __restrict__ addc,
                     const float* __restrict__ gop, const int* __restrict__ step,
                     const int* __restrict__ dflag) {
  const bool f32 = dflag[0] != 0;
  int row = blockIdx.x, t = threadIdx.x;
  int l = row >> 10, c = row & 1023;
  bool debate = (step[0] > 5) && (c < 256);
  size_t base = 513 + (size_t)row*HID;
#pragma unroll
  for (int k = 0; k < 4; ++k) {
    int j = t + k*256;
    float v = 0.7225f * ld1(outv, base + j, f32) + addc[l*HID + j];
    if (debate) v = 0.85f*v + 0.15f*gop[j];
    st1(outv, base + j, v, f32);
  }
}

extern "C" void kernel_launch(void* const* d_in, const int* in_sizes, int n_in,
                              void* d_out, int out_size, void* d_ws, size_t ws_size,
                              hipStream_t stream) {
  (void)in_sizes; (void)n_in; (void)out_size; (void)ws_size;
  const void* x    = d_in[0];
  const void* hid  = d_in[1];
  const void* eaW1 = d_in[2];
  const void* eab1 = d_in[3];
  const void* eaW2 = d_in[4];
  const void* eab2 = d_in[5];
  const void* egW1 = d_in[6];
  const void* egb1 = d_in[7];
  const void* egW2 = d_in[8];
  const void* egb2 = d_in[9];
  const void* gWih = d_in[10];
  const void* gWhh = d_in[11];
  const void* gbih = d_in[12];
  const void* gbhh = d_in[13];
  const void* pW1  = d_in[14];
  const void* pb1  = d_in[15];
  const void* pW2  = d_in[16];
  const void* pb2  = d_in[17];
  const void* peiW = d_in[18];
  const void* peib = d_in[19];
  const int*  step = (const int*)d_in[20];

  // ---- workspace layout (~20.06 MB, proven size) ----
  float* wsf = (float*)d_ws;
  float* tsum    = wsf + 0;       // 64
  float* baseacc = wsf + 64;      // 1024
  float* lm      = wsf + 1088;    // 4096
  float* pz      = wsf + 5184;    // 3072
  float* pe      = wsf + 8256;    // 3072
  float* comb    = wsf + 11328;   // 512 (+pad to 12288)
  int*   dflag   = (int*)(wsf + 12288);  // 64
  float* bs_r    = wsf + 12352;   // 4096
  float* bs_z    = wsf + 16448;   // 4096
  float* bn_i    = wsf + 20544;   // 4096
  float* bn_h    = wsf + 24640;   // 4096
  float* addc    = wsf + 28736;   // 4096
  float* gop     = wsf + 32832;   // 1024
  u16* Zb   = (u16*)(wsf + 33856);        // 4096*256
  u16* OUTT = Zb + (size_t)4096*256;      // 4096*544
  u16* WihP = OUTT + (size_t)4096*KP;     // 12288*544
  // W1T (4*256*1024 u16 = 2.1 MB) overlays OUTT: dead once k_z finishes,
  // before k_out writes OUTT.
  u16* W1T  = OUTT;

  k_detect   <<<dim3(1),        dim3(256), 0, stream>>>(x, dflag);
  k_prep     <<<dim3(64),       dim3(256), 0, stream>>>(wsf, gbih, gbhh, dflag,
                                                        bs_r, bs_z, bn_i, bn_h);
  k_prep_wih <<<dim3(12288),    dim3(256), 0, stream>>>(gWih, dflag, WihP);
  k_prep_w1t <<<dim3(4,2,8),    dim3(256), 0, stream>>>(eaW1, egW1, dflag, W1T);
  k_base_acc <<<dim3(4,2,4),    dim3(128), 0, stream>>>(x, eaW1, egW1, dflag, baseacc);
  k_z_mfma   <<<dim3(64,4),     dim3(256), 0, stream>>>(hid, W1T, eab1, egb1,
                                                        baseacc, dflag, Zb);
  k_out      <<<dim3(64,8),     dim3(256), 0, stream>>>(Zb, eaW2, egW2, eab2, egb2,
                                                        dflag, OUTT);
  k_tension  <<<dim3(4096),     dim3(256), 0, stream>>>(OUTT, tsum);
  k_gru_mfma <<<dim3(512),      dim3(256), 0, stream>>>(OUTT, hid, WihP, gWhh,
                                                        bs_r, bs_z, bn_i, bn_h,
                                                        dflag, d_out);
  k_lm_acc   <<<dim3(4,16),     dim3(256), 0, stream>>>(d_out, dflag, lm);
  k_lmfin    <<<dim3(16),       dim3(256), 0, stream>>>(lm);
  k_pz_acc   <<<dim3(3,4,8),    dim3(256), 0, stream>>>(lm, pW1, dflag, pz);
  k_pzfin    <<<dim3(12),       dim3(256), 0, stream>>>(pz, pb1, dflag);
  k_pe_acc   <<<dim3(3,4,8),    dim3(256), 0, stream>>>(pz, pW2, dflag, pe);
  k_pefin    <<<dim3(12),       dim3(256), 0, stream>>>(pe, pb2, lm, dflag);
  k_addc_gop <<<dim3(4),        dim3(256), 0, stream>>>(lm, pe, addc, gop);
  k_comb_acc <<<dim3(2,16),     dim3(256), 0, stream>>>(lm, peiW, dflag, comb);
  k_fin      <<<dim3(2),        dim3(256), 0, stream>>>(comb, peib, tsum, dflag, d_out);
  k_hh       <<<dim3(4096),     dim3(256), 0, stream>>>(d_out, addc, gop, step, dflag);
}

// Round 3
// 448.579 us; speedup vs baseline: 1.4916x; 1.3297x over previous
//
#include <hip/hip_runtime.h>
#include <math.h>

// Problem constants
#define L4   4
#define CPL  1024
#define HID  1024
#define IND  512
#define MLPD 128
#define OUTD 512
#define G3   3072
#define ROWS 4096   // L4*CPL
#define KP   544    // padded gi K: 512 OUT + 1 tension + 31 zeros

typedef unsigned short u16;
typedef u16   u16x8  __attribute__((ext_vector_type(8)));
typedef short bf16x8 __attribute__((ext_vector_type(8)));
typedef float f32x4  __attribute__((ext_vector_type(4)));

__device__ __forceinline__ float b2f(u16 u) {
  return __uint_as_float(((unsigned int)u) << 16);
}
__device__ __forceinline__ u16 f2b(float f) {   // round-to-nearest-even
  unsigned int x = __float_as_uint(f);
  x += 0x7fffu + ((x >> 16) & 1u);
  return (u16)(x >> 16);
}
__device__ __forceinline__ float sigm(float v) { return 1.0f/(1.0f + expf(-v)); }

// ---- dual-dtype access helpers: f32 flag selects float32 vs bf16 layout ----
struct F4 { float x, y, z, w; };
__device__ __forceinline__ F4 ld4(const void* p, size_t i, bool f32) {
  F4 r;
  if (f32) {
    float4 v = *reinterpret_cast<const float4*>((const float*)p + i);
    r.x = v.x; r.y = v.y; r.z = v.z; r.w = v.w;
  } else {
    ushort4 v = *reinterpret_cast<const ushort4*>((const u16*)p + i);
    r.x = b2f(v.x); r.y = b2f(v.y); r.z = b2f(v.z); r.w = b2f(v.w);
  }
  return r;
}
__device__ __forceinline__ float ld1(const void* p, size_t i, bool f32) {
  return f32 ? ((const float*)p)[i] : b2f(((const u16*)p)[i]);
}
__device__ __forceinline__ void st1(void* p, size_t i, float v, bool f32) {
  if (f32) ((float*)p)[i] = v; else ((u16*)p)[i] = f2b(v);
}
// load 8 elems -> bf16 bits (converting if fp32). i must be multiple of 8.
__device__ __forceinline__ u16x8 ldc8(const void* p, size_t i, bool f32) {
  u16x8 r;
  if (f32) {
    const float* q = (const float*)p + i;
    float4 v0 = *reinterpret_cast<const float4*>(q);
    float4 v1 = *reinterpret_cast<const float4*>(q + 4);
    r[0]=f2b(v0.x); r[1]=f2b(v0.y); r[2]=f2b(v0.z); r[3]=f2b(v0.w);
    r[4]=f2b(v1.x); r[5]=f2b(v1.y); r[6]=f2b(v1.z); r[7]=f2b(v1.w);
  } else {
    r = *reinterpret_cast<const u16x8*>((const u16*)p + i);
  }
  return r;
}

// ---------------- dtype detector ----------------
__global__ void k_detect(const void* __restrict__ x, int* __restrict__ flag) {
  int t = threadIdx.x;   // 256
  const u16* xu = (const u16*)x;
  unsigned u = xu[2*t];
  int e = (u >> 7) & 0xFF;
  int good = (e >= 96 && e <= 134) ? 1 : 0;
  __shared__ int cnt[256];
  cnt[t] = good;
  __syncthreads();
  for (int s = 128; s > 0; s >>= 1) { if (t < s) cnt[t] += cnt[t+s]; __syncthreads(); }
  if (t == 0) flag[0] = (cnt[0] < 200) ? 1 : 0;   // 1 = float32, 0 = bf16
}

// ---------------- prep: zero accumulators + bias sums ----------------
__global__ void k_prep(float* __restrict__ zf, const void* __restrict__ bih,
                       const void* __restrict__ bhh, const int* __restrict__ dflag,
                       float* __restrict__ bs_r, float* __restrict__ bs_z,
                       float* __restrict__ bn_i, float* __restrict__ bn_h) {
  const bool f32 = dflag[0] != 0;
  int b = blockIdx.x, t = threadIdx.x;
  if (b < 16) {
    int idx = b*256 + t;          // [0,4096)
    int l = idx >> 10, j = idx & 1023;
    bs_r[idx] = ld1(bih, l*G3 + j, f32)        + ld1(bhh, l*G3 + j, f32);
    bs_z[idx] = ld1(bih, l*G3 + 1024 + j, f32) + ld1(bhh, l*G3 + 1024 + j, f32);
    bn_i[idx] = ld1(bih, l*G3 + 2048 + j, f32);
    bn_h[idx] = ld1(bhh, l*G3 + 2048 + j, f32);
  } else {
    int idx = (b-16)*256 + t;     // [0,12288)
    zf[idx] = 0.0f;
  }
}

// ---------------- repack Wih -> bf16 [4][3072][544] (col 512 = tension wt) ----
__global__ void k_prep_wih(const void* __restrict__ Wih, const int* __restrict__ dflag,
                           u16* __restrict__ WihP) {
  const bool f32 = dflag[0] != 0;
  int row = blockIdx.x;            // 0..12287 == l*3072+g
  int t = threadIdx.x;
  size_t src = (size_t)row * 513;
  size_t dst = (size_t)row * KP;
  WihP[dst + t]       = f2b(ld1(Wih, src + t, f32));
  WihP[dst + 256 + t] = f2b(ld1(Wih, src + 256 + t, f32));
  if (t < 32) {
    float v = (t == 0) ? ld1(Wih, src + 512, f32) : 0.0f;
    WihP[dst + 512 + t] = f2b(v);
  }
}

// ---------------- convert Whh -> bf16 WhhP [4][3072][1024] ----------------
// 2 rows per block; thread handles 8 consecutive elems (vectorized via ldc8).
__global__ void k_prep_whh(const void* __restrict__ Whh, const int* __restrict__ dflag,
                           u16* __restrict__ WhhP) {
  const bool f32 = dflag[0] != 0;
  int t = threadIdx.x;
  int row = blockIdx.x*2 + (t >> 7);       // [0,12288)
  int c8  = (t & 127) * 8;                 // [0,1024) step 8
  size_t off = (size_t)row * HID + c8;
  u16x8 v = ldc8(Whh, off, f32);
  *reinterpret_cast<u16x8*>(&WhhP[off]) = v;
}

// ---------------- convert hiddens -> bf16 HB [4096][1024] ----------------
__global__ void k_prep_hb(const void* __restrict__ H, const int* __restrict__ dflag,
                          u16* __restrict__ HB) {
  const bool f32 = dflag[0] != 0;
  int t = threadIdx.x;
  int row = blockIdx.x*2 + (t >> 7);       // [0,4096)
  int c8  = (t & 127) * 8;
  size_t off = (size_t)row * HID + c8;
  u16x8 v = ldc8(H, off, f32);
  *reinterpret_cast<u16x8*>(&HB[off]) = v;
}

// ---------------- repack W1 hidden part -> bf16 transposed W1T[l][path*128+m][k] ----
// src: W1[l][512+k][m]  (k in [0,1024), m in [0,128)).  64-k-row tiles, 128 blocks.
__global__ void k_prep_w1t(const void* __restrict__ eaW1, const void* __restrict__ egW1,
                           const int* __restrict__ dflag, u16* __restrict__ W1T) {
  const bool f32 = dflag[0] != 0;
  __shared__ u16 sT[128*66];
  int l = blockIdx.x, path = blockIdx.y, kt = blockIdx.z;   // (4,2,16)
  int t = threadIdx.x;
  const void* W1 = path ? egW1 : eaW1;
  // read 64 k-rows x 128 m (coalesced over m), store transposed in LDS
  for (int rr = 0; rr < 64; rr += 2) {
    int r = rr + (t >> 7), m = t & 127;
    float v = ld1(W1, ((size_t)l*1536 + 512 + kt*64 + r)*MLPD + m, f32);
    sT[m*66 + r] = f2b(v);
  }
  __syncthreads();
  // write rows of W1T (coalesced over k)
  for (int mm = 0; mm < 128; mm += 4) {
    int m = mm + (t >> 6), kk = t & 63;
    W1T[((size_t)l*256 + path*128 + m)*1024 + kt*64 + kk] = sT[m*66 + kk];
  }
}

// ---------------- base accumulation (x part of encoder layer 1) ----------------
__global__ void k_base_acc(const void* __restrict__ x, const void* __restrict__ eaW1,
                           const void* __restrict__ egW1, const int* __restrict__ dflag,
                           float* __restrict__ baseacc) {
  const bool f32 = dflag[0] != 0;
  int l = blockIdx.x, path = blockIdx.y, kc = blockIdx.z, m = threadIdx.x; // 128 thr
  const void* W1 = path ? egW1 : eaW1;
  float acc = 0.0f;
  int i0 = kc*128;
  for (int i = i0; i < i0 + 128; ++i)
    acc += ld1(x, i, f32) * ld1(W1, ((size_t)l*1536 + i)*MLPD + m, f32);
  atomicAdd(&baseacc[path*512 + l*MLPD + m], acc);
}

// ---------------- MFMA k_z: Z = relu(base + b1 + HB @ W1T^T) ----------------
// A = HB [4096,1024] bf16, B = W1T [l][256][1024] bf16 (NT). Tile 64x64, 4 waves 2x2.
// dbuf LDS, one raw barrier per K-step; pure bf16 staging (no conversions).
#define LPAD 40
__global__ __launch_bounds__(256) void k_z_mfma(
    const u16* __restrict__ HB, const u16* __restrict__ W1T,
    const void* __restrict__ eab1, const void* __restrict__ egb1,
    const float* __restrict__ baseacc, const int* __restrict__ dflag,
    u16* __restrict__ Z) {
  const bool f32 = dflag[0] != 0;
  __shared__ u16 sA[2][64*LPAD];
  __shared__ u16 sB[2][64*LPAD];
  int t = threadIdx.x;
  int row0 = blockIdx.x * 64;
  int n0   = blockIdx.y * 64;          // 0,64,128,192
  int l    = row0 >> 10;
  int wid = t >> 6, lane = t & 63;
  int waveM = wid >> 1, waveN = wid & 1;
  int quad = lane >> 4, lcol = lane & 15;
  int arow = t >> 2, kq = (t & 3) * 8;

  f32x4 acc[2][2];
  const f32x4 zz = {0.0f,0.0f,0.0f,0.0f};
#pragma unroll
  for (int i = 0; i < 2; ++i)
#pragma unroll
    for (int j = 0; j < 2; ++j) acc[i][j] = zz;

  size_t habase = (size_t)(row0 + arow)*HID;
  const u16* Bb = W1T + ((size_t)l*256 + n0 + arow)*1024;

  u16x8 av = *reinterpret_cast<const u16x8*>(HB + habase + kq);
  u16x8 bv = *reinterpret_cast<const u16x8*>(Bb + kq);
  int cur = 0;
  for (int k0 = 0; k0 < HID; k0 += 32) {
    *reinterpret_cast<u16x8*>(&sA[cur][arow*LPAD + kq]) = av;
    *reinterpret_cast<u16x8*>(&sB[cur][arow*LPAD + kq]) = bv;
    asm volatile("s_waitcnt lgkmcnt(0)" ::: "memory");
    __builtin_amdgcn_s_barrier();
    if (k0 + 32 < HID) {
      av = *reinterpret_cast<const u16x8*>(HB + habase + k0 + 32 + kq);
      bv = *reinterpret_cast<const u16x8*>(Bb + k0 + 32 + kq);
    }
    bf16x8 af[2];
#pragma unroll
    for (int i = 0; i < 2; ++i)
      af[i] = *reinterpret_cast<const bf16x8*>(&sA[cur][(waveM*32 + i*16 + lcol)*LPAD + quad*8]);
#pragma unroll
    for (int j = 0; j < 2; ++j) {
      bf16x8 bf = *reinterpret_cast<const bf16x8*>(&sB[cur][(waveN*32 + j*16 + lcol)*LPAD + quad*8]);
#pragma unroll
      for (int i = 0; i < 2; ++i)
        acc[i][j] = __builtin_amdgcn_mfma_f32_16x16x32_bf16(af[i], bf, acc[i][j], 0, 0, 0);
    }
    cur ^= 1;
  }
  // epilogue: + base + b1, relu, store
#pragma unroll
  for (int j = 0; j < 2; ++j) {
    int nn = n0 + waveN*32 + j*16 + lcol;
    int path = nn >> 7, m = nn & 127;
    float bval = baseacc[path*512 + l*MLPD + m] +
                 ld1(path ? egb1 : eab1, l*MLPD + m, f32);
#pragma unroll
    for (int i = 0; i < 2; ++i)
#pragma unroll
      for (int g = 0; g < 4; ++g) {
        int r = row0 + waveM*32 + i*16 + quad*4 + g;
        float v = acc[i][j][g] + bval;
        Z[(size_t)r*256 + nn] = f2b(v > 0.0f ? v : 0.0f);
      }
  }
}

// ---------------- VALU k_out (small): OUT = Za@W2a - Zg@W2g + bias diff ----------------
#define BM 64
#define BN 64
#define BK 16
__global__ __launch_bounds__(256) void k_out(
    const u16* __restrict__ Zb, const void* __restrict__ eaW2, const void* __restrict__ egW2,
    const void* __restrict__ eab2, const void* __restrict__ egb2,
    const int* __restrict__ dflag, u16* __restrict__ OUTT) {
  const bool f32 = dflag[0] != 0;
  __shared__ float As[BK][BM];
  __shared__ float Bs[BK][BN];
  int t = threadIdx.x;
  int row0 = blockIdx.x * BM;
  int n0   = blockIdx.y * BN;          // 0..448
  int l    = row0 >> 10;
  const u16* Ab = Zb + (size_t)row0 * 256;
  int tx = t & 15, ty = t >> 4;
  int am = t >> 2, akq = (t & 3) * 4;
  int bk = t >> 4, bn = (t & 15) * 4;

  float acc[4][4];
#pragma unroll
  for (int j = 0; j < 4; ++j) {
    int o = n0 + tx*4 + j;
    float bd = ld1(eab2, l*OUTD + o, f32) - ld1(egb2, l*OUTD + o, f32);
#pragma unroll
    for (int i = 0; i < 4; ++i) acc[i][j] = bd;
  }
  for (int ph = 0; ph < 2; ++ph) {
    const void* B = ph ? egW2 : eaW2;
    size_t boff = (size_t)l*MLPD*OUTD + n0;
    float sgn = ph ? -1.0f : 1.0f;
    for (int k0 = 0; k0 < MLPD; k0 += BK) {
      ushort4 avu = *reinterpret_cast<const ushort4*>(Ab + (size_t)am*256 + ph*128 + k0 + akq);
      F4 bvf = ld4(B, boff + (size_t)(k0 + bk)*OUTD + bn, f32);
      __syncthreads();
      As[akq+0][am] = b2f(avu.x); As[akq+1][am] = b2f(avu.y);
      As[akq+2][am] = b2f(avu.z); As[akq+3][am] = b2f(avu.w);
      Bs[bk][bn+0] = sgn*bvf.x; Bs[bk][bn+1] = sgn*bvf.y;
      Bs[bk][bn+2] = sgn*bvf.z; Bs[bk][bn+3] = sgn*bvf.w;
      __syncthreads();
#pragma unroll
      for (int kk = 0; kk < BK; ++kk) {
        float4 a4 = *reinterpret_cast<const float4*>(&As[kk][ty*4]);
        float4 b4 = *reinterpret_cast<const float4*>(&Bs[kk][tx*4]);
        float a[4] = {a4.x,a4.y,a4.z,a4.w};
        float b[4] = {b4.x,b4.y,b4.z,b4.w};
#pragma unroll
        for (int i = 0; i < 4; ++i)
#pragma unroll
          for (int j = 0; j < 4; ++j) acc[i][j] += a[i]*b[j];
      }
    }
  }
#pragma unroll
  for (int i = 0; i < 4; ++i) {
    int r = row0 + ty*4 + i;
#pragma unroll
    for (int j = 0; j < 4; ++j)
      OUTT[(size_t)r*KP + n0 + tx*4 + j] = f2b(acc[i][j]);
  }
}

// tension -> OUTT col 512 (bf16); zero pad cols 513..543; tsum += sumsq(row)
__global__ void k_tension(u16* __restrict__ OUTT, float* __restrict__ tsum) {
  int row = blockIdx.x, t = threadIdx.x;
  u16* p = OUTT + (size_t)row*KP;
  float v0 = b2f(p[t]), v1 = b2f(p[t+256]);
  float s = v0*v0 + v1*v1;
#pragma unroll
  for (int off = 32; off > 0; off >>= 1) s += __shfl_down(s, off, 64);
  __shared__ float red[4];
  if ((t & 63) == 0) red[t >> 6] = s;
  __syncthreads();
  if (t == 0) {
    float tot = red[0] + red[1] + red[2] + red[3];
    p[512] = f2b(tot * (1.0f/512.0f));
    atomicAdd(tsum, tot);
  }
  if (t < 31) p[513 + t] = 0;
}

// ---------------- fused MFMA GRU v4: pure-bf16 staging, dbuf, 1 barrier/K-step ----
// Per block: 128 rows x 64 j-cols x {r,z,n} bands. 4 waves, each 64x32.
// stage(buf[cur]) -> lgkmcnt(0) -> raw s_barrier -> issue prefetch(t+1) ->
// MFMA(buf[cur]). Register staging: vmcnt never drains at a barrier. All hot-loop
// loads are pure u16x8 copies (WhhP/HB pre-converted) -> minimal VALU, half traffic.
#define SWZ(row, ku) ((row)*64 + ((ku) ^ (((row)&7)<<3)))
__global__ __launch_bounds__(256, 2) void k_gru_mfma(
    const u16* __restrict__ OUTT, const u16* __restrict__ HB,
    const u16* __restrict__ WihP, const u16* __restrict__ WhhP,
    const void* __restrict__ H,
    const float* __restrict__ bs_r, const float* __restrict__ bs_z,
    const float* __restrict__ bn_i, const float* __restrict__ bn_h,
    const int* __restrict__ dflag, void* __restrict__ outv) {
  const bool f32 = dflag[0] != 0;
  __shared__ __align__(16) u16 sA[2][128*64];     // 32 KB
  __shared__ __align__(16) u16 sB[2][3*64*64];    // 48 KB  (80 KB total, 2 blk/CU)
  int t = threadIdx.x;
  // XCD swizzle (512 blocks, 512%8==0 -> bijective): xg = XCD id.
  int bid = blockIdx.x;
  int xg = bid & 7, inner = bid >> 3;      // inner 0..63
  int l = xg & 3, jG = xg >> 2;
  int rbi = inner & 7, jbl = inner >> 3;   // 8 row-blocks, 8 j-blocks
  int row0 = (l*8 + rbi) * 128;
  int j0   = (jG*8 + jbl) * 64;
  int wid = t >> 6, lane = t & 63;
  int waveM = wid & 1, waveJ = wid >> 1;   // 2x2 waves over 128x64
  int quad = lane >> 4, lcol = lane & 15;

  f32x4 acc[4][4][2];   // band {r,z,i_n,h_n} x 4 m-frags x 2 j-frags
  const f32x4 zz = {0.0f,0.0f,0.0f,0.0f};
#pragma unroll
  for (int b = 0; b < 4; ++b)
#pragma unroll
    for (int i = 0; i < 4; ++i)
#pragma unroll
      for (int j = 0; j < 2; ++j) acc[b][i][j] = zz;

  // staging decomposition (per thread): A: 4 chunks, B: 6 chunks of u16x8.
  u16x8 ra[4], rbr[6];
  auto load1 = [&](int k0) {           // GEMM1 sources (zero-pad K tail)
    int kw = KP - k0;                  // 64 except last step (32)
#pragma unroll
    for (int s = 0; s < 4; ++s) {
      int idx = s*256 + t, row = idx >> 3, ch = idx & 7;
      if (ch*8 < kw)
        ra[s] = *reinterpret_cast<const u16x8*>(
            OUTT + (size_t)(row0 + row)*KP + k0 + ch*8);
      else { u16x8 z = {0,0,0,0,0,0,0,0}; ra[s] = z; }
    }
#pragma unroll
    for (int s = 0; s < 6; ++s) {
      int idx = s*256 + t, band = idx >> 9, rem = idx & 511;
      int row = rem >> 3, ch = rem & 7;
      if (ch*8 < kw)
        rbr[s] = *reinterpret_cast<const u16x8*>(
            WihP + ((size_t)l*G3 + band*1024 + j0 + row)*KP + k0 + ch*8);
      else { u16x8 z = {0,0,0,0,0,0,0,0}; rbr[s] = z; }
    }
  };
  auto load2 = [&](int k0) {           // GEMM2 sources (pure bf16)
#pragma unroll
    for (int s = 0; s < 4; ++s) {
      int idx = s*256 + t, row = idx >> 3, ch = idx & 7;
      ra[s] = *reinterpret_cast<const u16x8*>(
          HB + (size_t)(row0 + row)*HID + k0 + ch*8);
    }
#pragma unroll
    for (int s = 0; s < 6; ++s) {
      int idx = s*256 + t, band = idx >> 9, rem = idx & 511;
      int row = rem >> 3, ch = rem & 7;
      rbr[s] = *reinterpret_cast<const u16x8*>(
          WhhP + ((size_t)l*G3 + band*1024 + j0 + row)*HID + k0 + ch*8);
    }
  };
  auto stage = [&](int cb) {
#pragma unroll
    for (int s = 0; s < 4; ++s) {
      int idx = s*256 + t, row = idx >> 3, ch = idx & 7;
      *reinterpret_cast<u16x8*>(&sA[cb][SWZ(row, ch*8)]) = ra[s];
    }
#pragma unroll
    for (int s = 0; s < 6; ++s) {
      int idx = s*256 + t, band = idx >> 9, rem = idx & 511;
      int row = rem >> 3, ch = rem & 7;
      *reinterpret_cast<u16x8*>(&sB[cb][band*4096 + SWZ(row, ch*8)]) = rbr[s];
    }
  };

  int cur = 0;
  // ---- GEMM1: gi over K=544 (pure bf16; tail zero-padded -> no predicates) ----
  load1(0);
  for (int k0 = 0; k0 < KP; k0 += 64) {
    stage(cur);
    asm volatile("s_waitcnt lgkmcnt(0)" ::: "memory");
    __builtin_amdgcn_s_barrier();
    if (k0 + 64 < KP) load1(k0 + 64);
    else              load2(0);               // bridge into GEMM2
    __builtin_amdgcn_s_setprio(1);
#pragma unroll
    for (int kc = 0; kc < 2; ++kc) {
      bf16x8 af[4];
#pragma unroll
      for (int i = 0; i < 4; ++i) {
        int rl = waveM*64 + i*16 + lcol;
        af[i] = *reinterpret_cast<const bf16x8*>(&sA[cur][SWZ(rl, kc*32 + quad*8)]);
      }
#pragma unroll
      for (int b = 0; b < 3; ++b)
#pragma unroll
        for (int jj = 0; jj < 2; ++jj) {
          int jl = waveJ*32 + jj*16 + lcol;
          bf16x8 bf = *reinterpret_cast<const bf16x8*>(
              &sB[cur][b*4096 + SWZ(jl, kc*32 + quad*8)]);
#pragma unroll
          for (int i = 0; i < 4; ++i)
            acc[b][i][jj] = __builtin_amdgcn_mfma_f32_16x16x32_bf16(
                af[i], bf, acc[b][i][jj], 0, 0, 0);
        }
    }
    __builtin_amdgcn_s_setprio(0);
    cur ^= 1;
  }
  // ---- GEMM2: gh over K=1024 (pure bf16) ----
  for (int k0 = 0; k0 < HID; k0 += 64) {
    stage(cur);
    asm volatile("s_waitcnt lgkmcnt(0)" ::: "memory");
    __builtin_amdgcn_s_barrier();
    if (k0 + 64 < HID) load2(k0 + 64);
    __builtin_amdgcn_s_setprio(1);
#pragma unroll
    for (int kc = 0; kc < 2; ++kc) {
      bf16x8 af[4];
#pragma unroll
      for (int i = 0; i < 4; ++i) {
        int rl = waveM*64 + i*16 + lcol;
        af[i] = *reinterpret_cast<const bf16x8*>(&sA[cur][SWZ(rl, kc*32 + quad*8)]);
      }
#pragma unroll
      for (int b = 0; b < 3; ++b) {
        int ai = (b < 2) ? b : 3;
#pragma unroll
        for (int jj = 0; jj < 2; ++jj) {
          int jl = waveJ*32 + jj*16 + lcol;
          bf16x8 bf = *reinterpret_cast<const bf16x8*>(
              &sB[cur][b*4096 + SWZ(jl, kc*32 + quad*8)]);
#pragma unroll
          for (int i = 0; i < 4; ++i)
            acc[ai][i][jj] = __builtin_amdgcn_mfma_f32_16x16x32_bf16(
                af[i], bf, acc[ai][i][jj], 0, 0, 0);
        }
      }
    }
    __builtin_amdgcn_s_setprio(0);
    cur ^= 1;
  }
  // ---- epilogue: gates -> new_h into d_out hh region (exact f32 h blend) ----
#pragma unroll
  for (int i = 0; i < 4; ++i)
#pragma unroll
    for (int jj = 0; jj < 2; ++jj) {
      int j = j0 + waveJ*32 + jj*16 + lcol;
      float br = bs_r[l*HID + j], bz = bs_z[l*HID + j];
      float bi = bn_i[l*HID + j], bh = bn_h[l*HID + j];
#pragma unroll
      for (int g = 0; g < 4; ++g) {
        int r = row0 + waveM*64 + i*16 + quad*4 + g;
        float rg = sigm(acc[0][i][jj][g] + br);
        float zg = sigm(acc[1][i][jj][g] + bz);
        float ng = tanhf(acc[2][i][jj][g] + bi + rg*(acc[3][i][jj][g] + bh));
        float hv = ld1(H, (size_t)r*HID + j, f32);
        st1(outv, 513 + (size_t)r*HID + j, (1.0f - zg)*ng + zg*hv, f32);
      }
    }
}

// ---------------- level means (split-C atomics) ----------------
__global__ void k_lm_acc(const void* __restrict__ outv, const int* __restrict__ dflag,
                         float* __restrict__ lm) {
  const bool f32 = dflag[0] != 0;
  int l = blockIdx.x, cc = blockIdx.y, t = threadIdx.x;
  float s0=0.f, s1=0.f, s2=0.f, s3=0.f;
  for (int c = cc*16; c < cc*16 + 16; ++c) {
    size_t base = 513 + (size_t)(l*CPL + c)*HID;
    s0 += ld1(outv, base + t,       f32);
    s1 += ld1(outv, base + 256 + t, f32);
    s2 += ld1(outv, base + 512 + t, f32);
    s3 += ld1(outv, base + 768 + t, f32);
  }
  atomicAdd(&lm[l*HID + t],       s0);
  atomicAdd(&lm[l*HID + 256 + t], s1);
  atomicAdd(&lm[l*HID + 512 + t], s2);
  atomicAdd(&lm[l*HID + 768 + t], s3);
}
__global__ void k_lmfin(float* __restrict__ lm) {
  int idx = blockIdx.x*256 + threadIdx.x;
  lm[idx] *= (1.0f/1024.0f);
}

// ---------------- predictors (split-K atomics) ----------------
__global__ void k_pz_acc(const float* __restrict__ lm, const void* __restrict__ pW1,
                         const int* __restrict__ dflag, float* __restrict__ pz) {
  const bool f32 = dflag[0] != 0;
  int lv = blockIdx.x, mb = blockIdx.y, kc = blockIdx.z;
  int m = mb*256 + threadIdx.x;
  float acc = 0.0f;
  int i0 = kc*32;
  const float* lmp = lm + (lv + 1)*HID;
  for (int i = i0; i < i0 + 32; ++i)
    acc += lmp[i] * ld1(pW1, ((size_t)lv*HID + i)*HID + m, f32);
  atomicAdd(&pz[lv*HID + m], acc);
}
__global__ void k_pzfin(float* __restrict__ pz, const void* __restrict__ pb1,
                        const int* __restrict__ dflag) {
  const bool f32 = dflag[0] != 0;
  int idx = blockIdx.x*256 + threadIdx.x;   // [0,3072)
  float v = pz[idx] + ld1(pb1, idx, f32);
  pz[idx] = v > 0.0f ? v : 0.0f;
}
__global__ void k_pe_acc(const float* __restrict__ pz, const void* __restrict__ pW2,
                         const int* __restrict__ dflag, float* __restrict__ pe) {
  const bool f32 = dflag[0] != 0;
  int lv = blockIdx.x, ob = blockIdx.y, kc = blockIdx.z;
  int o = ob*256 + threadIdx.x;
  float acc = 0.0f;
  int m0 = kc*32;
  const float* pzp = pz + lv*HID;
  for (int m = m0; m < m0 + 32; ++m)
    acc += pzp[m] * ld1(pW2, ((size_t)lv*HID + m)*HID + o, f32);
  atomicAdd(&pe[lv*HID + o], acc);
}
__global__ void k_pefin(float* __restrict__ pe, const void* __restrict__ pb2,
                        const float* __restrict__ lm, const int* __restrict__ dflag) {
  const bool f32 = dflag[0] != 0;
  int idx = blockIdx.x*256 + threadIdx.x;   // [0,3072)
  pe[idx] = (pe[idx] + ld1(pb2, idx, f32) - lm[idx]) * 0.05f;
}

__global__ void k_addc_gop(const float* __restrict__ lm, const float* __restrict__ pe,
                           float* __restrict__ addc, float* __restrict__ gop) {
  int j = blockIdx.x*256 + threadIdx.x;
  float pe0 = pe[j], pe1 = pe[1024 + j], pe2 = pe[2048 + j];
  float d0 = pe0, d1 = pe1 - 0.5f*pe0, d2 = pe2 - 0.5f*pe1, d3 = -0.5f*pe2;
  float l0 = lm[j], l1 = lm[1024 + j], l2 = lm[2048 + j], l3 = lm[3072 + j];
  addc[j]        = 0.2775f*l0 + d0;
  addc[1024 + j] = 0.2775f*l1 + d1;
  addc[2048 + j] = 0.2775f*l2 + d2;
  addc[3072 + j] = 0.2775f*l3 + d3;
  gop[j] = 0.25f*((l0 + d0) + (l1 + d1) + (l2 + d2) + (l3 + d3));
}

__global__ void k_comb_acc(const float* __restrict__ lm, const void* __restrict__ peiW,
                           const int* __restrict__ dflag, float* __restrict__ comb) {
  const bool f32 = dflag[0] != 0;
  int ob = blockIdx.x, kc = blockIdx.y;
  int o = ob*256 + threadIdx.x;
  float acc = 0.0f;
  int i0 = kc*128;
  for (int i = i0; i < i0 + 128; ++i)
    acc += lm[i] * ld1(peiW, (size_t)i*OUTD + o, f32);
  atomicAdd(&comb[o], acc);
}
__global__ void k_fin(const float* __restrict__ comb, const void* __restrict__ peib,
                      const float* __restrict__ tsum, const int* __restrict__ dflag,
                      void* __restrict__ outv) {
  const bool f32 = dflag[0] != 0;
  int o = blockIdx.x*256 + threadIdx.x;
  st1(outv, o, comb[o] + ld1(peib, o, f32), f32);
  if (o == 0) st1(outv, 512, tsum[0] * (1.0f/(4096.0f*512.0f)), f32);
}

__global__ void k_hh(void* __restrict__ outv, const float* __restrict__ addc,
                     const float* __restrict__ gop, const int* __restrict__ step,
                     const int* __restrict__ dflag) {
  const bool f32 = dflag[0] != 0;
  int row = blockIdx.x, t = threadIdx.x;
  int l = row >> 10, c = row & 1023;
  bool debate = (step[0] > 5) && (c < 256);
  size_t base = 513 + (size_t)row*HID;
#pragma unroll
  for (int k = 0; k < 4; ++k) {
    int j = t + k*256;
    float v = 0.7225f * ld1(outv, base + j, f32) + addc[l*HID + j];
    if (debate) v = 0.85f*v + 0.15f*gop[j];
    st1(outv, base + j, v, f32);
  }
}

extern "C" void kernel_launch(void* const* d_in, const int* in_sizes, int n_in,
                              void* d_out, int out_size, void* d_ws, size_t ws_size,
                              hipStream_t stream) {
  (void)in_sizes; (void)n_in; (void)out_size; (void)ws_size;
  const void* x    = d_in[0];
  const void* hid  = d_in[1];
  const void* eaW1 = d_in[2];
  const void* eab1 = d_in[3];
  const void* eaW2 = d_in[4];
  const void* eab2 = d_in[5];
  const void* egW1 = d_in[6];
  const void* egb1 = d_in[7];
  const void* egW2 = d_in[8];
  const void* egb2 = d_in[9];
  const void* gWih = d_in[10];
  const void* gWhh = d_in[11];
  const void* gbih = d_in[12];
  const void* gbhh = d_in[13];
  const void* pW1  = d_in[14];
  const void* pb1  = d_in[15];
  const void* pW2  = d_in[16];
  const void* pb2  = d_in[17];
  const void* peiW = d_in[18];
  const void* peib = d_in[19];
  const int*  step = (const int*)d_in[20];

  // ---- workspace layout (~53.6 MB) ----
  float* wsf = (float*)d_ws;
  float* tsum    = wsf + 0;       // 64
  float* baseacc = wsf + 64;      // 1024
  float* lm      = wsf + 1088;    // 4096
  float* pz      = wsf + 5184;    // 3072
  float* pe      = wsf + 8256;    // 3072
  float* comb    = wsf + 11328;   // 512 (+pad to 12288)
  int*   dflag   = (int*)(wsf + 12288);  // 64
  float* bs_r    = wsf + 12352;   // 4096
  float* bs_z    = wsf + 16448;   // 4096
  float* bn_i    = wsf + 20544;   // 4096
  float* bn_h    = wsf + 24640;   // 4096
  float* addc    = wsf + 28736;   // 4096
  float* gop     = wsf + 32832;   // 1024
  u16* Zb   = (u16*)(wsf + 33856);        // 4096*256
  u16* OUTT = Zb + (size_t)4096*256;      // 4096*544
  u16* WihP = OUTT + (size_t)4096*KP;     // 12288*544
  u16* HB   = WihP + (size_t)12288*KP;    // 4096*1024  (bf16 hiddens)
  u16* WhhP = HB   + (size_t)4096*1024;   // 12288*1024 (bf16 Whh)
  // W1T (4*256*1024 u16 = 2.1 MB) overlays OUTT: dead once k_z finishes,
  // before k_out writes OUTT.
  u16* W1T  = OUTT;

  k_detect   <<<dim3(1),        dim3(256), 0, stream>>>(x, dflag);
  k_prep     <<<dim3(64),       dim3(256), 0, stream>>>(wsf, gbih, gbhh, dflag,
                                                        bs_r, bs_z, bn_i, bn_h);
  k_prep_wih <<<dim3(12288),    dim3(256), 0, stream>>>(gWih, dflag, WihP);
  k_prep_whh <<<dim3(6144),     dim3(256), 0, stream>>>(gWhh, dflag, WhhP);
  k_prep_hb  <<<dim3(2048),     dim3(256), 0, stream>>>(hid, dflag, HB);
  k_prep_w1t <<<dim3(4,2,16),   dim3(256), 0, stream>>>(eaW1, egW1, dflag, W1T);
  k_base_acc <<<dim3(4,2,4),    dim3(128), 0, stream>>>(x, eaW1, egW1, dflag, baseacc);
  k_z_mfma   <<<dim3(64,4),     dim3(256), 0, stream>>>(HB, W1T, eab1, egb1,
                                                        baseacc, dflag, Zb);
  k_out      <<<dim3(64,8),     dim3(256), 0, stream>>>(Zb, eaW2, egW2, eab2, egb2,
                                                        dflag, OUTT);
  k_tension  <<<dim3(4096),     dim3(256), 0, stream>>>(OUTT, tsum);
  k_gru_mfma <<<dim3(512),      dim3(256), 0, stream>>>(OUTT, HB, WihP, WhhP, hid,
                                                        bs_r, bs_z, bn_i, bn_h,
                                                        dflag, d_out);
  k_lm_acc   <<<dim3(4,64),     dim3(256), 0, stream>>>(d_out, dflag, lm);
  k_lmfin    <<<dim3(16),       dim3(256), 0, stream>>>(lm);
  k_pz_acc   <<<dim3(3,4,32),   dim3(256), 0, stream>>>(lm, pW1, dflag, pz);
  k_pzfin    <<<dim3(12),       dim3(256), 0, stream>>>(pz, pb1, dflag);
  k_pe_acc   <<<dim3(3,4,32),   dim3(256), 0, stream>>>(pz, pW2, dflag, pe);
  k_pefin    <<<dim3(12),       dim3(256), 0, stream>>>(pe, pb2, lm, dflag);
  k_addc_gop <<<dim3(4),        dim3(256), 0, stream>>>(lm, pe, addc, gop);
  k_comb_acc <<<dim3(2,32),     dim3(256), 0, stream>>>(lm, peiW, dflag, comb);
  k_fin      <<<dim3(2),        dim3(256), 0, stream>>>(comb, peib, tsum, dflag, d_out);
  k_hh       <<<dim3(4096),     dim3(256), 0, stream>>>(d_out, addc, gop, step, dflag);
}